// Round 1
// baseline (2758.325 us; speedup 1.0000x reference)
//
#include <hip/hip_runtime.h>

typedef unsigned short u16;
typedef unsigned int u32;

typedef short bf16x8 __attribute__((ext_vector_type(8)));
typedef float f32x4 __attribute__((ext_vector_type(4)));

#define T_SEQ 2048
#define HV 32
#define HK 16

__device__ __forceinline__ u16 f2bf(float f) {
    u32 u = __float_as_uint(f);
    u += 0x7fffu + ((u >> 16) & 1u);
    return (u16)(u >> 16);
}
__device__ __forceinline__ float bf2f(u16 s) {
    return __uint_as_float(((u32)s) << 16);
}

// ---------------- K0: cast fp32 -> bf16 (elementwise) ----------------
__global__ __launch_bounds__(256) void cast_f32_bf16(const float* __restrict__ in,
                                                     u16* __restrict__ out, long n) {
    long i = ((long)blockIdx.x * 256 + threadIdx.x) * 4;
    if (i + 3 < n) {
        float4 v = *(const float4*)&in[i];
        out[i + 0] = f2bf(v.x);
        out[i + 1] = f2bf(v.y);
        out[i + 2] = f2bf(v.z);
        out[i + 3] = f2bf(v.w);
    }
}

// ---------------- K1/K2: transpose + cast: in [R,C] fp32 -> out [C,R] bf16 ----------------
__global__ __launch_bounds__(256) void transpose_cast(const float* __restrict__ in,
                                                      u16* __restrict__ out, int R, int C) {
    __shared__ float tile[32][33];
    int c0 = blockIdx.x * 32, r0 = blockIdx.y * 32;
    int tx = threadIdx.x & 31, ty = threadIdx.x >> 5;  // ty in 0..7
#pragma unroll
    for (int rr = 0; rr < 32; rr += 8)
        tile[ty + rr][tx] = in[(long)(r0 + ty + rr) * C + c0 + tx];
    __syncthreads();
#pragma unroll
    for (int rr = 0; rr < 32; rr += 8)
        out[(long)(c0 + ty + rr) * R + r0 + tx] = f2bf(tile[tx][ty + rr]);
}

// ---------------- GEMM: C[M,N] = A[M,K] * BT[N,K], bf16 in, fp32 acc ----------------
// 128x128 block tile, BK=32, 256 threads = 4 waves in 2x2, each wave 64x64 = 4x4 MFMA tiles.
template <bool OUT_BF16>
__global__ __launch_bounds__(256) void gemm_bt(const u16* __restrict__ A,
                                               const u16* __restrict__ B, void* __restrict__ C,
                                               int M, int N, int K, int lda, int ldb, int ldc) {
    __shared__ __align__(16) u16 As[128 * 32];
    __shared__ __align__(16) u16 Bs[128 * 32];
    int m0 = blockIdx.y * 128, n0 = blockIdx.x * 128;
    int tid = threadIdx.x;
    int lane = tid & 63, w = tid >> 6;
    int wr = w >> 1, wc = w & 1;
    int quad = lane >> 4, l15 = lane & 15;

    f32x4 acc[4][4];
#pragma unroll
    for (int i = 0; i < 4; i++)
#pragma unroll
        for (int j = 0; j < 4; j++) acc[i][j] = (f32x4){0.f, 0.f, 0.f, 0.f};

    for (int k0 = 0; k0 < K; k0 += 32) {
#pragma unroll
        for (int pass = 0; pass < 2; ++pass) {
            int slot = pass * 256 + tid;  // 0..511, 8 bf16 each
            int row = slot >> 2;
            int c8 = slot & 3;
            *(uint4*)&As[row * 32 + c8 * 8] =
                *(const uint4*)&A[(long)(m0 + row) * lda + k0 + c8 * 8];
            *(uint4*)&Bs[row * 32 + c8 * 8] =
                *(const uint4*)&B[(long)(n0 + row) * ldb + k0 + c8 * 8];
        }
        __syncthreads();
        bf16x8 af[4], bfr[4];
#pragma unroll
        for (int i = 0; i < 4; i++) {
            int ml = wr * 64 + i * 16 + l15;
            af[i] = *(const bf16x8*)&As[ml * 32 + quad * 8];
            int nl = wc * 64 + i * 16 + l15;
            bfr[i] = *(const bf16x8*)&Bs[nl * 32 + quad * 8];
        }
#pragma unroll
        for (int i = 0; i < 4; i++)
#pragma unroll
            for (int j = 0; j < 4; j++)
                acc[i][j] = __builtin_amdgcn_mfma_f32_16x16x32_bf16(af[i], bfr[j], acc[i][j], 0, 0, 0);
        __syncthreads();
    }
#pragma unroll
    for (int i = 0; i < 4; i++) {
#pragma unroll
        for (int j = 0; j < 4; j++) {
#pragma unroll
            for (int r = 0; r < 4; r++) {
                int row = m0 + wr * 64 + i * 16 + quad * 4 + r;
                int col = n0 + wc * 64 + j * 16 + l15;
                float val = acc[i][j][r];
                if (OUT_BF16)
                    ((u16*)C)[(long)row * ldc + col] = f2bf(val);
                else
                    ((float*)C)[(long)row * ldc + col] = val;
            }
        }
    }
}

// ---------------- K4: ba = hidden @ W_ba -> g, beta ----------------
__global__ __launch_bounds__(256) void ba_gate(const float* __restrict__ hidden,
                                               const float* __restrict__ W_ba,
                                               const float* __restrict__ A_log,
                                               const float* __restrict__ dt_bias,
                                               float* __restrict__ g, float* __restrict__ beta) {
    int tok = blockIdx.x, tid = threadIdx.x;
    __shared__ float sh_h[2048];
    __shared__ float sh_p[256];
#pragma unroll
    for (int i = 0; i < 8; i++) sh_h[i * 256 + tid] = hidden[(long)tok * 2048 + i * 256 + tid];
    __syncthreads();
    int outc = tid & 63, part = tid >> 6;
    float acc = 0.f;
    for (int i = 0; i < 512; i++) acc += sh_h[part * 512 + i] * W_ba[(long)(part * 512 + i) * 64 + outc];
    sh_p[tid] = acc;
    __syncthreads();
    if (tid < 64) {
        float tot = sh_p[tid] + sh_p[tid + 64] + sh_p[tid + 128] + sh_p[tid + 192];
        if (tid < 32) {
            beta[(long)tok * 32 + tid] = 1.f / (1.f + expf(-tot));
        } else {
            int h = tid - 32;
            float x = tot + dt_bias[h];
            float sp = (x > 20.f) ? x : log1pf(expf(x));
            g[(long)tok * 32 + h] = -expf(A_log[h]) * sp;
        }
    }
}

// ---------------- K5: causal conv + SiLU + l2norm + split ----------------
__global__ __launch_bounds__(256) void conv_gate(const u16* __restrict__ qkvz,
                                                 const float* __restrict__ conv_w,
                                                 u16* __restrict__ qn, u16* __restrict__ kn,
                                                 u16* __restrict__ vc) {
    int tok = blockIdx.x, tid = threadIdx.x;
    int tloc = tok & (T_SEQ - 1);
    __shared__ float mixed[8192];
    __shared__ float sh_norm[32];
#pragma unroll 4
    for (int i = 0; i < 32; i++) {
        int c = i * 256 + tid;
        const float* wp = &conv_w[(long)c * 4];
        float w0 = wp[0], w1 = wp[1], w2 = wp[2], w3 = wp[3];
        float acc = bf2f(qkvz[(long)tok * 12288 + c]) * w3;
        if (tloc >= 1) acc += bf2f(qkvz[(long)(tok - 1) * 12288 + c]) * w2;
        if (tloc >= 2) acc += bf2f(qkvz[(long)(tok - 2) * 12288 + c]) * w1;
        if (tloc >= 3) acc += bf2f(qkvz[(long)(tok - 3) * 12288 + c]) * w0;
        mixed[c] = acc / (1.f + expf(-acc));  // SiLU
    }
    __syncthreads();
    // l2 norms for 32 groups of 128 (16 q heads + 16 k heads)
    int grp = tid >> 3, sub = tid & 7;
    float ss = 0.f;
#pragma unroll
    for (int e = 0; e < 16; e++) {
        float v = mixed[grp * 128 + sub * 16 + e];
        ss += v * v;
    }
    ss += __shfl_xor(ss, 4, 8);
    ss += __shfl_xor(ss, 2, 8);
    ss += __shfl_xor(ss, 1, 8);
    if (sub == 0) sh_norm[grp] = rsqrtf(ss + 1e-6f);
    __syncthreads();
#pragma unroll 4
    for (int i = 0; i < 32; i++) {
        int c = i * 256 + tid;
        float m = mixed[c];
        if (c < 2048) {
            qn[(long)tok * 2048 + c] = f2bf(m * sh_norm[c >> 7] * 0.08838834764831845f);  // K^-0.5
        } else if (c < 4096) {
            kn[(long)tok * 2048 + (c - 2048)] = f2bf(m * sh_norm[c >> 7]);
        } else {
            vc[(long)tok * 4096 + (c - 4096)] = f2bf(m);
        }
    }
}

// ---------------- K6: gated delta rule scan ----------------
// grid: 256 blocks = (b:2) x (h:32) x (vchunk:4). 256 threads.
// thread owns S[kh*16 .. kh*16+16)[v = vci*32 + (tid&31)] in 16 registers.
__global__ __launch_bounds__(256) void delta_scan(const u16* __restrict__ qn,
                                                  const u16* __restrict__ kn,
                                                  const u16* __restrict__ vc,
                                                  const float* __restrict__ g,
                                                  const float* __restrict__ beta,
                                                  u16* __restrict__ obuf) {
    int bid = blockIdx.x;
    int vci = bid & 3;
    int h = (bid >> 2) & 31;
    int b = bid >> 7;
    int hk = h >> 1;
    int tid = threadIdx.x;
    int vloc = tid & 31, kh = tid >> 5;

    __shared__ float sh_k[128], sh_q[128], sh_v[32], sh_p1[256], sh_p2[256];

    float s[16];
#pragma unroll
    for (int i = 0; i < 16; i++) s[i] = 0.f;

    // prefetch t=0
    float r_kq, r_v = 0.f, r_g, r_b;
    {
        long tok = (long)b * T_SEQ;
        long bqk = tok * 2048 + hk * 128;
        r_kq = (tid < 128) ? bf2f(kn[bqk + tid]) : bf2f(qn[bqk + tid - 128]);
        if (tid < 32) r_v = bf2f(vc[tok * 4096 + h * 128 + vci * 32 + tid]);
        r_g = g[tok * 32 + h];
        r_b = beta[tok * 32 + h];
    }

    for (int t = 0; t < T_SEQ; ++t) {
        // deposit prefetched step t
        if (tid < 128) sh_k[tid] = r_kq;
        else sh_q[tid - 128] = r_kq;
        if (tid < 32) sh_v[tid] = r_v;
        float alpha = expf(r_g);
        float bet = r_b;
        __syncthreads();  // A
        // prefetch t+1 (overlaps compute)
        if (t + 1 < T_SEQ) {
            long tok = (long)b * T_SEQ + t + 1;
            long bqk = tok * 2048 + hk * 128;
            r_kq = (tid < 128) ? bf2f(kn[bqk + tid]) : bf2f(qn[bqk + tid - 128]);
            if (tid < 32) r_v = bf2f(vc[tok * 4096 + h * 128 + vci * 32 + tid]);
            r_g = g[tok * 32 + h];
            r_b = beta[tok * 32 + h];
        }
        // pass 1: decay + k·S partial
        float p = 0.f;
#pragma unroll
        for (int i = 0; i < 16; i++) {
            float sv = s[i] * alpha;
            s[i] = sv;
            p += sh_k[kh * 16 + i] * sv;
        }
        sh_p1[tid] = p;
        __syncthreads();  // B
        float pred = 0.f;
#pragma unroll
        for (int j = 0; j < 8; j++) pred += sh_p1[vloc + j * 32];
        float delta = (sh_v[vloc] - pred) * bet;
        // pass 2: rank-1 update + q·S partial
        float oo = 0.f;
#pragma unroll
        for (int i = 0; i < 16; i++) {
            float sv = s[i] + sh_k[kh * 16 + i] * delta;
            s[i] = sv;
            oo += sh_q[kh * 16 + i] * sv;
        }
        sh_p2[tid] = oo;
        __syncthreads();  // C
        if (tid < 32) {
            float ot = 0.f;
#pragma unroll
            for (int j = 0; j < 8; j++) ot += sh_p2[tid + j * 32];
            obuf[((long)b * T_SEQ + t) * 4096 + h * 128 + vci * 32 + tid] = f2bf(ot);
        }
    }
}

// ---------------- K7: gated RMSNorm: x = o*silu(z); per-head RMS; -> xn bf16 ----------------
__global__ __launch_bounds__(256) void gated_norm(const u16* __restrict__ obuf,
                                                  const u16* __restrict__ qkvz,
                                                  const float* __restrict__ norm_w,
                                                  u16* __restrict__ xn) {
    int tok = blockIdx.x, tid = threadIdx.x;
    long obase = (long)tok * 4096 + tid * 16;
    long zbase = (long)tok * 12288 + 8192 + tid * 16;
    u16 ob[16], zb[16];
    *(uint4*)(ob + 0) = *(const uint4*)&obuf[obase];
    *(uint4*)(ob + 8) = *(const uint4*)&obuf[obase + 8];
    *(uint4*)(zb + 0) = *(const uint4*)&qkvz[zbase];
    *(uint4*)(zb + 8) = *(const uint4*)&qkvz[zbase + 8];
    float x[16];
    float ss = 0.f;
#pragma unroll
    for (int i = 0; i < 16; i++) {
        float ov = bf2f(ob[i]);
        float zv = bf2f(zb[i]);
        float xv = ov * (zv / (1.f + expf(-zv)));
        x[i] = xv;
        ss += xv * xv;
    }
    // 8 threads per head of 128
    ss += __shfl_xor(ss, 4, 8);
    ss += __shfl_xor(ss, 2, 8);
    ss += __shfl_xor(ss, 1, 8);
    float scale = rsqrtf(ss * (1.f / 128.f) + 1e-6f);
    int cbase = (tid * 16) & 127;
#pragma unroll
    for (int i = 0; i < 16; i++)
        xn[(long)tok * 4096 + tid * 16 + i] = f2bf(x[i] * scale * (1.f + norm_w[cbase + i]));
}

// ---------------- launch ----------------
extern "C" void kernel_launch(void* const* d_in, const int* in_sizes, int n_in, void* d_out,
                              int out_size, void* d_ws, size_t ws_size, hipStream_t stream) {
    const float* hidden = (const float*)d_in[0];   // [2,2048,2048]
    const float* W_qkvz = (const float*)d_in[1];   // [2048,12288]
    const float* W_ba = (const float*)d_in[2];     // [2048,64]
    const float* conv_w = (const float*)d_in[3];   // [8192,4]
    const float* A_log = (const float*)d_in[4];    // [32]
    const float* dt_bias = (const float*)d_in[5];  // [32]
    const float* norm_w = (const float*)d_in[6];   // [128]
    const float* W_out = (const float*)d_in[7];    // [4096,2048]
    float* out = (float*)d_out;                    // [2,2048,2048] fp32

    char* ws = (char*)d_ws;
    // layout (bytes):
    //   [0,             50331648)  wqT bf16 [12288,2048]; later kn[16.7MB]+vc[33.5MB]; later xn
    //   [50331648,      67108864)  hid bf16 [4096,2048];  later qn
    //   [67108864,      83886080)  woT bf16 [2048,4096]
    //   [83886080,     184549376)  qkvz bf16 [4096,12288]
    //   [184549376,    185073664)  g   fp32 [4096,32]
    //   [185073664,    185597952)  beta fp32 [4096,32]
    //   [185597952,    219152384)  o   bf16 [4096,4096]
    u16* wqT = (u16*)(ws + 0);
    u16* hidbf = (u16*)(ws + 50331648L);
    u16* woT = (u16*)(ws + 67108864L);
    u16* qkvz = (u16*)(ws + 83886080L);
    float* g = (float*)(ws + 184549376L);
    float* beta = (float*)(ws + 185073664L);
    u16* obuf = (u16*)(ws + 185597952L);
    u16* kn = (u16*)(ws + 0);
    u16* vc = (u16*)(ws + 16777216L);
    u16* qn = hidbf;
    u16* xn = (u16*)(ws + 0);

    cast_f32_bf16<<<8192, 256, 0, stream>>>(hidden, hidbf, 8388608L);
    transpose_cast<<<dim3(384, 64), 256, 0, stream>>>(W_qkvz, wqT, 2048, 12288);
    transpose_cast<<<dim3(64, 128), 256, 0, stream>>>(W_out, woT, 4096, 2048);
    gemm_bt<true><<<dim3(96, 32), 256, 0, stream>>>(hidbf, wqT, qkvz, 4096, 12288, 2048, 2048,
                                                    2048, 12288);
    ba_gate<<<4096, 256, 0, stream>>>(hidden, W_ba, A_log, dt_bias, g, beta);
    conv_gate<<<4096, 256, 0, stream>>>(qkvz, conv_w, qn, kn, vc);
    delta_scan<<<256, 256, 0, stream>>>(qn, kn, vc, g, beta, obuf);
    gated_norm<<<4096, 256, 0, stream>>>(obuf, qkvz, norm_w, xn);
    gemm_bt<false><<<dim3(16, 32), 256, 0, stream>>>(xn, woT, out, 4096, 2048, 4096, 4096, 4096,
                                                     2048);
}

// Round 2
// 1188.380 us; speedup vs baseline: 2.3211x; 2.3211x over previous
//
#include <hip/hip_runtime.h>

typedef unsigned short u16;
typedef unsigned int u32;

typedef short bf16x8 __attribute__((ext_vector_type(8)));
typedef float f32x4 __attribute__((ext_vector_type(4)));

#define T_SEQ 2048
#define MFMA16(a, b, c) __builtin_amdgcn_mfma_f32_16x16x32_bf16(a, b, c, 0, 0, 0)

__device__ __forceinline__ u16 f2bf(float f) {
    u32 u = __float_as_uint(f);
    u += 0x7fffu + ((u >> 16) & 1u);
    return (u16)(u >> 16);
}
__device__ __forceinline__ float bf2f(u16 s) {
    return __uint_as_float(((u32)s) << 16);
}

// ---------------- cast fp32 -> bf16 ----------------
__global__ __launch_bounds__(256) void cast_f32_bf16(const float* __restrict__ in,
                                                     u16* __restrict__ out, long n) {
    long i = ((long)blockIdx.x * 256 + threadIdx.x) * 4;
    if (i + 3 < n) {
        float4 v = *(const float4*)&in[i];
        out[i + 0] = f2bf(v.x);
        out[i + 1] = f2bf(v.y);
        out[i + 2] = f2bf(v.z);
        out[i + 3] = f2bf(v.w);
    }
}

// ---------------- transpose + cast: [R,C] f32 -> [C,R] bf16 ----------------
__global__ __launch_bounds__(256) void transpose_cast(const float* __restrict__ in,
                                                      u16* __restrict__ out, int R, int C) {
    __shared__ float tile[32][33];
    int c0 = blockIdx.x * 32, r0 = blockIdx.y * 32;
    int tx = threadIdx.x & 31, ty = threadIdx.x >> 5;
#pragma unroll
    for (int rr = 0; rr < 32; rr += 8)
        tile[ty + rr][tx] = in[(long)(r0 + ty + rr) * C + c0 + tx];
    __syncthreads();
#pragma unroll
    for (int rr = 0; rr < 32; rr += 8)
        out[(long)(c0 + ty + rr) * R + r0 + tx] = f2bf(tile[tx][ty + rr]);
}

// ---------------- GEMM: C[M,N] = A[M,K] * BT[N,K] ----------------
// MODE 0: f32 out (ldc) ; MODE 1: bf16 out (ldc) ; MODE 2: split bf16 qkv(8192)/z(4096)
template <int MODE>
__global__ __launch_bounds__(256) void gemm_bt(const u16* __restrict__ A,
                                               const u16* __restrict__ B, void* __restrict__ C,
                                               void* __restrict__ C2, int M, int N, int K, int lda,
                                               int ldb, int ldc) {
    __shared__ __align__(16) u16 As[128 * 32];
    __shared__ __align__(16) u16 Bs[128 * 32];
    int m0 = blockIdx.y * 128, n0 = blockIdx.x * 128;
    int tid = threadIdx.x;
    int lane = tid & 63, w = tid >> 6;
    int wr = w >> 1, wc = w & 1;
    int quad = lane >> 4, l15 = lane & 15;

    f32x4 acc[4][4];
#pragma unroll
    for (int i = 0; i < 4; i++)
#pragma unroll
        for (int j = 0; j < 4; j++) acc[i][j] = (f32x4){0.f, 0.f, 0.f, 0.f};

    for (int k0 = 0; k0 < K; k0 += 32) {
#pragma unroll
        for (int pass = 0; pass < 2; ++pass) {
            int slot = pass * 256 + tid;
            int row = slot >> 2;
            int c8 = slot & 3;
            *(uint4*)&As[row * 32 + c8 * 8] =
                *(const uint4*)&A[(long)(m0 + row) * lda + k0 + c8 * 8];
            *(uint4*)&Bs[row * 32 + c8 * 8] =
                *(const uint4*)&B[(long)(n0 + row) * ldb + k0 + c8 * 8];
        }
        __syncthreads();
        bf16x8 af[4], bfr[4];
#pragma unroll
        for (int i = 0; i < 4; i++) {
            af[i] = *(const bf16x8*)&As[(wr * 64 + i * 16 + l15) * 32 + quad * 8];
            bfr[i] = *(const bf16x8*)&Bs[(wc * 64 + i * 16 + l15) * 32 + quad * 8];
        }
#pragma unroll
        for (int i = 0; i < 4; i++)
#pragma unroll
            for (int j = 0; j < 4; j++) acc[i][j] = MFMA16(af[i], bfr[j], acc[i][j]);
        __syncthreads();
    }
#pragma unroll
    for (int i = 0; i < 4; i++) {
#pragma unroll
        for (int j = 0; j < 4; j++) {
#pragma unroll
            for (int r = 0; r < 4; r++) {
                int row = m0 + wr * 64 + i * 16 + quad * 4 + r;
                int col = n0 + wc * 64 + j * 16 + l15;
                float val = acc[i][j][r];
                if (MODE == 0)
                    ((float*)C)[(long)row * ldc + col] = val;
                else if (MODE == 1)
                    ((u16*)C)[(long)row * ldc + col] = f2bf(val);
                else {
                    if (col < 8192)
                        ((u16*)C)[(long)row * 8192 + col] = f2bf(val);
                    else
                        ((u16*)C2)[(long)row * 4096 + col - 8192] = f2bf(val);
                }
            }
        }
    }
}

// ---------------- ba = hidden @ W_ba -> g, beta ----------------
__global__ __launch_bounds__(256) void ba_gate(const float* __restrict__ hidden,
                                               const float* __restrict__ W_ba,
                                               const float* __restrict__ A_log,
                                               const float* __restrict__ dt_bias,
                                               float* __restrict__ g, float* __restrict__ beta) {
    int tok = blockIdx.x, tid = threadIdx.x;
    __shared__ float sh_h[2048];
    __shared__ float sh_p[256];
#pragma unroll
    for (int i = 0; i < 8; i++) sh_h[i * 256 + tid] = hidden[(long)tok * 2048 + i * 256 + tid];
    __syncthreads();
    int outc = tid & 63, part = tid >> 6;
    float acc = 0.f;
    for (int i = 0; i < 512; i++)
        acc += sh_h[part * 512 + i] * W_ba[(long)(part * 512 + i) * 64 + outc];
    sh_p[tid] = acc;
    __syncthreads();
    if (tid < 64) {
        float tot = sh_p[tid] + sh_p[tid + 64] + sh_p[tid + 128] + sh_p[tid + 192];
        if (tid < 32) {
            beta[(long)tok * 32 + tid] = 1.f / (1.f + expf(-tot));
        } else {
            int h = tid - 32;
            float x = tot + dt_bias[h];
            float sp = (x > 20.f) ? x : log1pf(expf(x));
            g[(long)tok * 32 + h] = -expf(A_log[h]) * sp;
        }
    }
}

// ---------------- causal conv + SiLU + l2norm + split ----------------
__global__ __launch_bounds__(256) void conv_gate(const u16* __restrict__ qkv,
                                                 const float* __restrict__ conv_w,
                                                 u16* __restrict__ qn, u16* __restrict__ kn,
                                                 u16* __restrict__ vc) {
    int tok = blockIdx.x, tid = threadIdx.x;
    int tloc = tok & (T_SEQ - 1);
    __shared__ float mixed[8192];
    __shared__ float sh_norm[32];
#pragma unroll 4
    for (int i = 0; i < 32; i++) {
        int c = i * 256 + tid;
        const float* wp = &conv_w[(long)c * 4];
        float w0 = wp[0], w1 = wp[1], w2 = wp[2], w3 = wp[3];
        float acc = bf2f(qkv[(long)tok * 8192 + c]) * w3;
        if (tloc >= 1) acc += bf2f(qkv[(long)(tok - 1) * 8192 + c]) * w2;
        if (tloc >= 2) acc += bf2f(qkv[(long)(tok - 2) * 8192 + c]) * w1;
        if (tloc >= 3) acc += bf2f(qkv[(long)(tok - 3) * 8192 + c]) * w0;
        mixed[c] = acc / (1.f + expf(-acc));
    }
    __syncthreads();
    int grp = tid >> 3, sub = tid & 7;
    float ss = 0.f;
#pragma unroll
    for (int e = 0; e < 16; e++) {
        float v = mixed[grp * 128 + sub * 16 + e];
        ss += v * v;
    }
    ss += __shfl_xor(ss, 4, 8);
    ss += __shfl_xor(ss, 2, 8);
    ss += __shfl_xor(ss, 1, 8);
    if (sub == 0) sh_norm[grp] = rsqrtf(ss + 1e-6f);
    __syncthreads();
#pragma unroll 4
    for (int i = 0; i < 32; i++) {
        int c = i * 256 + tid;
        float m = mixed[c];
        if (c < 2048) {
            qn[(long)tok * 2048 + c] = f2bf(m * sh_norm[c >> 7] * 0.08838834764831845f);
        } else if (c < 4096) {
            kn[(long)tok * 2048 + (c - 2048)] = f2bf(m * sh_norm[c >> 7]);
        } else {
            vc[(long)tok * 4096 + (c - 4096)] = f2bf(m);
        }
    }
}

// ---------------- phase A: per-chunk WY transform ----------------
// block = (b, h, chunk); C=64. Outputs: Tv=T*V, Tw=T*W (bf16 [64][128]),
// Q2 = Qtilde - L*Tw, O_loc = L*Tv -> obuf (aliases vc).
__global__ __launch_bounds__(256) void phaseA(const u16* __restrict__ qn,
                                              const u16* __restrict__ kn,
                                              const u16* __restrict__ vc,
                                              const float* __restrict__ g,
                                              const float* __restrict__ beta,
                                              u16* __restrict__ Tv_g, u16* __restrict__ Tw_g,
                                              u16* __restrict__ Q2_g, u16* __restrict__ obuf) {
    __shared__ __align__(16) u16 Yrm[64][256];    // 32 KB: row i, cols: [Tv(128) | Tw(128)]
    __shared__ __align__(16) float BMt[64][64];   // 16 KB: BMt[j][i] = beta_i*Gram[i,j]*decay
    __shared__ __align__(16) u16 kbuf[64][128];   // 16 KB: k tile; later L (bf16 [64][64])
    u16* Lbf = &kbuf[0][0];

    int bid = blockIdx.x;
    int c = bid & 31, h = (bid >> 5) & 31, b = bid >> 10;
    int hk = h >> 1;
    long tokbase = (long)b * T_SEQ + c * 64;
    long cb = (long)bid * 8192;
    int tid = threadIdx.x, lane = tid & 63, w = tid >> 6;
    int quad = lane >> 4, l15 = lane & 15;

    // per-wave replicated gate values + inclusive cumsum of g
    float gl = g[(tokbase + lane) * 32 + h];
    float bl = beta[(tokbase + lane) * 32 + h];
    float cgl = gl;
#pragma unroll
    for (int d = 1; d < 64; d <<= 1) {
        float y = __shfl_up(cgl, d);
        if (lane >= d) cgl += y;
    }
    float wscl = bl * __expf(cgl);  // beta_i * exp(cg_i)
    float eCgl = __expf(cgl);       // exp(cg_i)

#pragma unroll
    for (int p = 0; p < 4; p++) {
        int u = p * 256 + tid;
        int row = u >> 4, col8 = (u & 15) * 8;
        *(uint4*)&kbuf[row][col8] = *(const uint4*)&kn[(tokbase + row) * 2048 + hk * 128 + col8];
    }
    __syncthreads();

    // Gram_kk -> BMt
    {
        f32x4 gk[4];
#pragma unroll
        for (int nj = 0; nj < 4; nj++) gk[nj] = (f32x4){0.f, 0.f, 0.f, 0.f};
#pragma unroll
        for (int kk = 0; kk < 4; kk++) {
            bf16x8 a = *(const bf16x8*)&kbuf[w * 16 + l15][kk * 32 + quad * 8];
#pragma unroll
            for (int nj = 0; nj < 4; nj++) {
                bf16x8 bb = *(const bf16x8*)&kbuf[nj * 16 + l15][kk * 32 + quad * 8];
                gk[nj] = MFMA16(a, bb, gk[nj]);
            }
        }
#pragma unroll
        for (int nj = 0; nj < 4; nj++)
#pragma unroll
            for (int r = 0; r < 4; r++) {
                int i = w * 16 + quad * 4 + r;
                int j = nj * 16 + l15;
                float cgi = __shfl(cgl, i), cgj = __shfl(cgl, j);
                float bi = __shfl(bl, i);
                BMt[j][i] = (j < i) ? bi * gk[nj][r] * __expf(cgi - cgj) : 0.f;
            }
    }
    __syncthreads();

    // blocked forward substitution: (I+BM) Y = B*[V | W]
    {
        int col = tid;
        bool isV = col < 128;
        int kcol = col & 127;
        long vbase = tokbase * 4096 + h * 128 + kcol;
        float Yreg[8], acc8[8];
#pragma unroll 1
        for (int bi = 0; bi < 8; ++bi) {
            float vr[8];
            if (isV) {
#pragma unroll
                for (int ii = 0; ii < 8; ii++)
                    vr[ii] = bf2f(vc[vbase + (long)(bi * 8 + ii) * 4096]);
            }
#pragma unroll
            for (int ii = 0; ii < 8; ii++) acc8[ii] = 0.f;
            for (int j = 0; j < bi * 8; ++j) {
                float yv = bf2f(Yrm[j][col]);
                float4 m0 = *(const float4*)&BMt[j][bi * 8];
                float4 m1 = *(const float4*)&BMt[j][bi * 8 + 4];
                acc8[0] += m0.x * yv;
                acc8[1] += m0.y * yv;
                acc8[2] += m0.z * yv;
                acc8[3] += m0.w * yv;
                acc8[4] += m1.x * yv;
                acc8[5] += m1.y * yv;
                acc8[6] += m1.z * yv;
                acc8[7] += m1.w * yv;
            }
#pragma unroll
            for (int ii = 0; ii < 8; ii++) {
                int i = bi * 8 + ii;
                float rhs = isV ? __shfl(bl, i) * vr[ii] : __shfl(wscl, i) * bf2f(kbuf[i][kcol]);
                float s = rhs - acc8[ii];
#pragma unroll
                for (int jj = 0; jj < 8; jj++)
                    if (jj < ii) s -= BMt[bi * 8 + jj][i] * Yreg[jj];
                Yreg[ii] = s;
                u16 sb = f2bf(s);
                Yrm[i][col] = sb;
                if (isV)
                    Tv_g[cb + i * 128 + kcol] = sb;
                else
                    Tw_g[cb + i * 128 + kcol] = sb;
            }
        }
    }
    __syncthreads();

    // Gram_qk -> L (bf16, into kbuf region)
    {
        f32x4 qk_[4];
#pragma unroll
        for (int nj = 0; nj < 4; nj++) qk_[nj] = (f32x4){0.f, 0.f, 0.f, 0.f};
#pragma unroll
        for (int kk = 0; kk < 4; kk++) {
            bf16x8 a = *(const bf16x8*)&qn[(tokbase + w * 16 + l15) * 2048 + hk * 128 + kk * 32 +
                                           quad * 8];
#pragma unroll
            for (int nj = 0; nj < 4; nj++) {
                bf16x8 bb = *(const bf16x8*)&kbuf[nj * 16 + l15][kk * 32 + quad * 8];
                qk_[nj] = MFMA16(a, bb, qk_[nj]);
            }
        }
        __syncthreads();  // all kbuf reads done before Lbf overwrite
#pragma unroll
        for (int nj = 0; nj < 4; nj++)
#pragma unroll
            for (int r = 0; r < 4; r++) {
                int t = w * 16 + quad * 4 + r;
                int rr = nj * 16 + l15;
                float cgt = __shfl(cgl, t), cgr = __shfl(cgl, rr);
                float val = (rr <= t) ? qk_[nj][r] * __expf(cgt - cgr) : 0.f;
                Lbf[t * 64 + rr] = f2bf(val);
            }
    }
    __syncthreads();

    // O_loc = L*Tv -> obuf ; Q2 = Qtilde - L*Tw
#pragma unroll 1
    for (int half = 0; half < 2; half++) {
        f32x4 oa[8];
#pragma unroll
        for (int nj = 0; nj < 8; nj++) oa[nj] = (f32x4){0.f, 0.f, 0.f, 0.f};
#pragma unroll
        for (int kk = 0; kk < 2; kk++) {
            bf16x8 a = *(const bf16x8*)&Lbf[(w * 16 + l15) * 64 + kk * 32 + quad * 8];
#pragma unroll
            for (int nj = 0; nj < 8; nj++) {
                bf16x8 bb;
#pragma unroll
                for (int jj = 0; jj < 8; jj++)
                    bb[jj] = (short)Yrm[kk * 32 + quad * 8 + jj][half * 128 + nj * 16 + l15];
                oa[nj] = MFMA16(a, bb, oa[nj]);
            }
        }
        if (half == 0) {
#pragma unroll
            for (int nj = 0; nj < 8; nj++)
#pragma unroll
                for (int r = 0; r < 4; r++) {
                    int t = w * 16 + quad * 4 + r;
                    int vcol = nj * 16 + l15;
                    obuf[(tokbase + t) * 4096 + h * 128 + vcol] = f2bf(oa[nj][r]);
                }
        } else {
#pragma unroll
            for (int nj = 0; nj < 8; nj++)
#pragma unroll
                for (int r = 0; r < 4; r++) {
                    int t = w * 16 + quad * 4 + r;
                    int kcol = nj * 16 + l15;
                    float qsc = __shfl(eCgl, t);
                    float qv = bf2f(qn[(tokbase + t) * 2048 + hk * 128 + kcol]);
                    Q2_g[cb + t * 128 + kcol] = f2bf(qsc * qv - oa[nj][r]);
                }
        }
    }
}

// ---------------- phase B: sequential chunk recurrence (32 steps) ----------------
// block = (b, h, vquarter). S[kdim=128][vloc=32] fp32 in LDS + bf16 transposed copy.
__global__ __launch_bounds__(256) void phaseB(const u16* __restrict__ kn,
                                              const float* __restrict__ g,
                                              const u16* __restrict__ Tv_g,
                                              const u16* __restrict__ Tw_g,
                                              const u16* __restrict__ Q2_g,
                                              u16* __restrict__ obuf) {
    __shared__ __align__(16) float Sf[128][32];  // 16 KB master state
    __shared__ __align__(16) u16 SbfT[32][128];  // 8 KB  [vloc][kdim]
    __shared__ __align__(16) u16 KhT[128][64];   // 16 KB [kdim][s]
    __shared__ __align__(16) u16 Ut[32][64];     // 4 KB  [vloc][s]

    int bid = blockIdx.x;
    int vq = bid & 3, h = (bid >> 2) & 31, b = bid >> 7;
    int hk = h >> 1;
    int tid = threadIdx.x, lane = tid & 63, w = tid >> 6;
    int quad = lane >> 4, l15 = lane & 15;

    for (int p = tid; p < 128 * 32; p += 256) {
        ((float*)Sf)[p] = 0.f;
        ((u16*)SbfT)[p] = 0;
    }
    __syncthreads();

    for (int c = 0; c < 32; ++c) {
        long tokbase = (long)b * T_SEQ + c * 64;
        long cb = (long)(((b * 32 + h) * 32) + c) * 8192;
        // decay scan
        float gl = g[(tokbase + lane) * 32 + h];
        float cgl = gl;
#pragma unroll
        for (int d = 1; d < 64; d <<= 1) {
            float y = __shfl_up(cgl, d);
            if (lane >= d) cgl += y;
        }
        float cgC = __shfl(cgl, 63);
        float A_C = __expf(cgC);
        float kscl = __expf(cgC - cgl);

        // build KhT[kdim][s] = exp(cgC - cg_s) * k[s][kdim]
        {
            int s = tid >> 2, qq = tid & 3;
            float ksc = __shfl(kscl, s);
            const u16* kp = &kn[(tokbase + s) * 2048 + hk * 128 + qq * 32];
            u16 tmp[32];
            *(uint4*)&tmp[0] = *(const uint4*)&kp[0];
            *(uint4*)&tmp[8] = *(const uint4*)&kp[8];
            *(uint4*)&tmp[16] = *(const uint4*)&kp[16];
            *(uint4*)&tmp[24] = *(const uint4*)&kp[24];
#pragma unroll
            for (int j = 0; j < 32; j++) KhT[qq * 32 + j][s] = f2bf(bf2f(tmp[j]) * ksc);
        }

        // Y1 = Tw*S0 ; O = Q2*S0 (wave w -> token tile w)
        f32x4 y1[2], oo[2];
#pragma unroll
        for (int nj = 0; nj < 2; nj++) {
            y1[nj] = (f32x4){0.f, 0.f, 0.f, 0.f};
            oo[nj] = (f32x4){0.f, 0.f, 0.f, 0.f};
        }
#pragma unroll
        for (int kk = 0; kk < 4; kk++) {
            bf16x8 aTw = *(const bf16x8*)&Tw_g[cb + (w * 16 + l15) * 128 + kk * 32 + quad * 8];
            bf16x8 aQ2 = *(const bf16x8*)&Q2_g[cb + (w * 16 + l15) * 128 + kk * 32 + quad * 8];
#pragma unroll
            for (int nj = 0; nj < 2; nj++) {
                bf16x8 bb = *(const bf16x8*)&SbfT[nj * 16 + l15][kk * 32 + quad * 8];
                y1[nj] = MFMA16(aTw, bb, y1[nj]);
                oo[nj] = MFMA16(aQ2, bb, oo[nj]);
            }
        }
        // U = Tv - Y1 ; O += O_loc (RMW obuf)
#pragma unroll
        for (int nj = 0; nj < 2; nj++)
#pragma unroll
            for (int r = 0; r < 4; r++) {
                int i = w * 16 + quad * 4 + r;
                int vl = nj * 16 + l15;
                int vg = vq * 32 + vl;
                float tvv = bf2f(Tv_g[cb + (long)i * 128 + vg]);
                Ut[vl][i] = f2bf(tvv - y1[nj][r]);
                long op = (tokbase + i) * 4096 + h * 128 + vg;
                obuf[op] = f2bf(bf2f(obuf[op]) + oo[nj][r]);
            }
        __syncthreads();  // KhT, Ut ready; SbfT reads complete

        // S = A_C*S + KhT^T... (wave w -> kdim tiles 2w, 2w+1)
#pragma unroll
        for (int mm = 0; mm < 2; mm++) {
            int mi = 2 * w + mm;
#pragma unroll
            for (int nj = 0; nj < 2; nj++) {
                f32x4 sacc;
#pragma unroll
                for (int r = 0; r < 4; r++)
                    sacc[r] = A_C * Sf[mi * 16 + quad * 4 + r][nj * 16 + l15];
#pragma unroll
                for (int kk = 0; kk < 2; kk++) {
                    bf16x8 a = *(const bf16x8*)&KhT[mi * 16 + l15][kk * 32 + quad * 8];
                    bf16x8 bb = *(const bf16x8*)&Ut[nj * 16 + l15][kk * 32 + quad * 8];
                    sacc = MFMA16(a, bb, sacc);
                }
#pragma unroll
                for (int r = 0; r < 4; r++) {
                    int kd = mi * 16 + quad * 4 + r, vl = nj * 16 + l15;
                    Sf[kd][vl] = sacc[r];
                    SbfT[vl][kd] = f2bf(sacc[r]);
                }
            }
        }
        __syncthreads();
    }
}

// ---------------- gated RMSNorm ----------------
__global__ __launch_bounds__(256) void gated_norm(const u16* __restrict__ obuf,
                                                  const u16* __restrict__ zbuf,
                                                  const float* __restrict__ norm_w,
                                                  u16* __restrict__ xn) {
    int tok = blockIdx.x, tid = threadIdx.x;
    long obase = (long)tok * 4096 + tid * 16;
    u16 ob[16], zb[16];
    *(uint4*)(ob + 0) = *(const uint4*)&obuf[obase];
    *(uint4*)(ob + 8) = *(const uint4*)&obuf[obase + 8];
    *(uint4*)(zb + 0) = *(const uint4*)&zbuf[obase];
    *(uint4*)(zb + 8) = *(const uint4*)&zbuf[obase + 8];
    float x[16];
    float ss = 0.f;
#pragma unroll
    for (int i = 0; i < 16; i++) {
        float ov = bf2f(ob[i]);
        float zv = bf2f(zb[i]);
        float xv = ov * (zv / (1.f + expf(-zv)));
        x[i] = xv;
        ss += xv * xv;
    }
    ss += __shfl_xor(ss, 4, 8);
    ss += __shfl_xor(ss, 2, 8);
    ss += __shfl_xor(ss, 1, 8);
    float scale = rsqrtf(ss * (1.f / 128.f) + 1e-6f);
    int cbase = (tid * 16) & 127;
#pragma unroll
    for (int i = 0; i < 16; i++)
        xn[(long)tok * 4096 + tid * 16 + i] = f2bf(x[i] * scale * (1.f + norm_w[cbase + i]));
}

// ---------------- launch ----------------
extern "C" void kernel_launch(void* const* d_in, const int* in_sizes, int n_in, void* d_out,
                              int out_size, void* d_ws, size_t ws_size, hipStream_t stream) {
    const float* hidden = (const float*)d_in[0];
    const float* W_qkvz = (const float*)d_in[1];
    const float* W_ba = (const float*)d_in[2];
    const float* conv_w = (const float*)d_in[3];
    const float* A_log = (const float*)d_in[4];
    const float* dt_bias = (const float*)d_in[5];
    const float* norm_w = (const float*)d_in[6];
    const float* W_out = (const float*)d_in[7];
    float* out = (float*)d_out;

    char* ws = (char*)d_ws;
    // [0,        50331648)  wqT            -> later qn@0, vc/obuf@16777216
    // [50331648, 67108864)  hidbf          -> later kn
    // [67108864, 83886080)  woT            (persistent)
    // [83886080, 150994944) qkv_raw        -> later Tv@83886080, Tw@117440512 -> later xn@83886080
    // [150994944,184549376) zbuf           (persistent)
    // [184549376,218103808) Q2
    // [218103808,218628096) g
    // [218628096,219152384) beta
    u16* wqT = (u16*)(ws + 0);
    u16* qn = (u16*)(ws + 0);
    u16* vc = (u16*)(ws + 16777216L);  // also obuf (O_loc written in place)
    u16* hidbf = (u16*)(ws + 50331648L);
    u16* kn = (u16*)(ws + 50331648L);
    u16* woT = (u16*)(ws + 67108864L);
    u16* qkv_raw = (u16*)(ws + 83886080L);
    u16* Tv = (u16*)(ws + 83886080L);
    u16* Tw = (u16*)(ws + 117440512L);
    u16* xn = (u16*)(ws + 83886080L);
    u16* zbuf = (u16*)(ws + 150994944L);
    u16* Q2 = (u16*)(ws + 184549376L);
    float* g = (float*)(ws + 218103808L);
    float* beta = (float*)(ws + 218628096L);
    u16* obuf = vc;

    cast_f32_bf16<<<8192, 256, 0, stream>>>(hidden, hidbf, 8388608L);
    transpose_cast<<<dim3(384, 64), 256, 0, stream>>>(W_qkvz, wqT, 2048, 12288);
    transpose_cast<<<dim3(64, 128), 256, 0, stream>>>(W_out, woT, 4096, 2048);
    gemm_bt<2><<<dim3(96, 32), 256, 0, stream>>>(hidbf, wqT, qkv_raw, zbuf, 4096, 12288, 2048,
                                                 2048, 2048, 0);
    ba_gate<<<4096, 256, 0, stream>>>(hidden, W_ba, A_log, dt_bias, g, beta);
    conv_gate<<<4096, 256, 0, stream>>>(qkv_raw, conv_w, qn, kn, vc);
    phaseA<<<2048, 256, 0, stream>>>(qn, kn, vc, g, beta, Tv, Tw, Q2, obuf);
    phaseB<<<256, 256, 0, stream>>>(kn, g, Tv, Tw, Q2, obuf);
    gated_norm<<<4096, 256, 0, stream>>>(obuf, zbuf, norm_w, xn);
    gemm_bt<0><<<dim3(16, 32), 256, 0, stream>>>(xn, woT, out, nullptr, 4096, 2048, 4096, 4096,
                                                 4096, 2048);
}

// Round 3
// 1120.204 us; speedup vs baseline: 2.4623x; 1.0609x over previous
//
#include <hip/hip_runtime.h>

typedef unsigned short u16;
typedef unsigned int u32;

typedef short bf16x8 __attribute__((ext_vector_type(8)));
typedef float f32x4 __attribute__((ext_vector_type(4)));

#define T_SEQ 2048
#define MFMA16(a, b, c) __builtin_amdgcn_mfma_f32_16x16x32_bf16(a, b, c, 0, 0, 0)

__device__ __forceinline__ u16 f2bf(float f) {
    u32 u = __float_as_uint(f);
    u += 0x7fffu + ((u >> 16) & 1u);
    return (u16)(u >> 16);
}
__device__ __forceinline__ float bf2f(u16 s) {
    return __uint_as_float(((u32)s) << 16);
}
// async global->LDS, 16B per lane; LDS dest = wave-uniform base + lane*16
__device__ __forceinline__ void g2lds16(const u16* gp, u16* lp) {
    __builtin_amdgcn_global_load_lds((const __attribute__((address_space(1))) void*)gp,
                                     (__attribute__((address_space(3))) void*)lp, 16, 0, 0);
}

// ---------------- cast fp32 -> bf16 ----------------
__global__ __launch_bounds__(256) void cast_f32_bf16(const float* __restrict__ in,
                                                     u16* __restrict__ out, long n) {
    long i = ((long)blockIdx.x * 256 + threadIdx.x) * 4;
    if (i + 3 < n) {
        float4 v = *(const float4*)&in[i];
        out[i + 0] = f2bf(v.x);
        out[i + 1] = f2bf(v.y);
        out[i + 2] = f2bf(v.z);
        out[i + 3] = f2bf(v.w);
    }
}

// ---------------- transpose + cast: [R,C] f32 -> [C,R] bf16 ----------------
__global__ __launch_bounds__(256) void transpose_cast(const float* __restrict__ in,
                                                      u16* __restrict__ out, int R, int C) {
    __shared__ float tile[32][33];
    int c0 = blockIdx.x * 32, r0 = blockIdx.y * 32;
    int tx = threadIdx.x & 31, ty = threadIdx.x >> 5;
#pragma unroll
    for (int rr = 0; rr < 32; rr += 8)
        tile[ty + rr][tx] = in[(long)(r0 + ty + rr) * C + c0 + tx];
    __syncthreads();
#pragma unroll
    for (int rr = 0; rr < 32; rr += 8)
        out[(long)(c0 + ty + rr) * R + r0 + tx] = f2bf(tile[tx][ty + rr]);
}

// ---------------- GEMM: C[M,N] = A[M,K] * BT[N,K] ----------------
// MODE 0: f32 out (ldc) ; MODE 2: split bf16 qkv(cols<8192, ld 8192)/z(ld 4096)
// grid: x = M-tiles, y = N-tiles (consecutive blocks stream A, share B-tile)
template <int MODE>
__global__ __launch_bounds__(256) void gemm_bt(const u16* __restrict__ A,
                                               const u16* __restrict__ B, void* __restrict__ C,
                                               void* __restrict__ C2, int M, int N, int K, int lda,
                                               int ldb, int ldc) {
    __shared__ __align__(16) u16 As[128 * 32];
    __shared__ __align__(16) u16 Bs[128 * 32];
    int m0 = blockIdx.x * 128, n0 = blockIdx.y * 128;
    int tid = threadIdx.x;
    int lane = tid & 63, w = tid >> 6;
    int wr = w >> 1, wc = w & 1;
    int quad = lane >> 4, l15 = lane & 15;

    f32x4 acc[4][4];
#pragma unroll
    for (int i = 0; i < 4; i++)
#pragma unroll
        for (int j = 0; j < 4; j++) acc[i][j] = (f32x4){0.f, 0.f, 0.f, 0.f};

    int srow = tid >> 2, sc8 = (tid & 3) * 8;
    const u16* Ag = &A[(long)(m0 + srow) * lda + sc8];
    const u16* Bg = &B[(long)(n0 + srow) * ldb + sc8];

    for (int k0 = 0; k0 < K; k0 += 32) {
        g2lds16(Ag + k0, &As[tid * 8]);
        g2lds16(Ag + (long)64 * lda + k0, &As[(256 + tid) * 8]);
        g2lds16(Bg + k0, &Bs[tid * 8]);
        g2lds16(Bg + (long)64 * ldb + k0, &Bs[(256 + tid) * 8]);
        __syncthreads();
        bf16x8 af[4], bfr[4];
#pragma unroll
        for (int i = 0; i < 4; i++) {
            af[i] = *(const bf16x8*)&As[(wr * 64 + i * 16 + l15) * 32 + quad * 8];
            bfr[i] = *(const bf16x8*)&Bs[(wc * 64 + i * 16 + l15) * 32 + quad * 8];
        }
#pragma unroll
        for (int i = 0; i < 4; i++)
#pragma unroll
            for (int j = 0; j < 4; j++) acc[i][j] = MFMA16(af[i], bfr[j], acc[i][j]);
        __syncthreads();
    }

    if (MODE == 0) {
#pragma unroll
        for (int i = 0; i < 4; i++)
#pragma unroll
            for (int j = 0; j < 4; j++)
#pragma unroll
                for (int r = 0; r < 4; r++) {
                    int row = m0 + wr * 64 + i * 16 + quad * 4 + r;
                    int col = n0 + wc * 64 + j * 16 + l15;
                    ((float*)C)[(long)row * ldc + col] = acc[i][j][r];
                }
    } else {
        // vectorized epilogue: stage C halves (128x64 bf16 = 16KB) through As/Bs LDS
        u16* Cst = As;  // As(8KB)+Bs(8KB) contiguous? not guaranteed; use As only: need 16KB
        // As is 128*32 u16 = 8KB. Use both via address of As and Bs separately per half-row.
        // Simpler: declare overlay over As for rows 0..63 and Bs for rows 64..127.
        u16* dst;
        long dldc;
        int ncol0;
        if (MODE == 2 && n0 >= 8192) {
            dst = (u16*)C2;
            dldc = 4096;
            ncol0 = n0 - 8192;
        } else {
            dst = (u16*)C;
            dldc = (MODE == 2) ? 8192 : ldc;
            ncol0 = n0;
        }
#pragma unroll 1
        for (int half = 0; half < 2; half++) {
            __syncthreads();
            if (wc == half) {
#pragma unroll
                for (int i = 0; i < 4; i++)
#pragma unroll
                    for (int j = 0; j < 4; j++)
#pragma unroll
                        for (int r = 0; r < 4; r++) {
                            int row = wr * 64 + i * 16 + quad * 4 + r;  // 0..127
                            int col = j * 16 + l15;                     // 0..63
                            u16* base = (row < 64) ? As : Bs;
                            base[(row & 63) * 64 + col] = f2bf(acc[i][j][r]);
                        }
            }
            __syncthreads();
#pragma unroll
            for (int rr = 0; rr < 4; rr++) {
                int row = rr * 32 + (tid >> 3), seg = tid & 7;
                u16* base = (row < 64) ? As : Bs;
                *(uint4*)&dst[(long)(m0 + row) * dldc + ncol0 + half * 64 + seg * 8] =
                    *(uint4*)&base[(row & 63) * 64 + seg * 8];
            }
        }
    }
}

// ---------------- ba = hidden @ W_ba -> g, beta (MFMA, fused epilogue) ----------------
// grid 128 blocks: each 32 tokens x 64 outputs, K=2048. W_baT: [64][2048] bf16.
__global__ __launch_bounds__(256) void ba_gemm(const u16* __restrict__ hid,
                                               const u16* __restrict__ WbaT,
                                               const float* __restrict__ A_log,
                                               const float* __restrict__ dt_bias,
                                               float* __restrict__ g, float* __restrict__ beta) {
    __shared__ __align__(16) u16 As2[32 * 32];
    int m0 = blockIdx.x * 32;
    int tid = threadIdx.x, lane = tid & 63, w = tid >> 6;
    int quad = lane >> 4, l15 = lane & 15;
    int trow = w & 1;
    int ctile = (w >> 1) * 2;
    f32x4 acc[2];
    acc[0] = (f32x4){0.f, 0.f, 0.f, 0.f};
    acc[1] = (f32x4){0.f, 0.f, 0.f, 0.f};
    for (int k0 = 0; k0 < 2048; k0 += 32) {
        if (tid < 128) {
            int row = tid >> 2, c8 = (tid & 3) * 8;
            *(uint4*)&As2[row * 32 + c8] = *(const uint4*)&hid[(long)(m0 + row) * 2048 + k0 + c8];
        }
        __syncthreads();
        bf16x8 a = *(const bf16x8*)&As2[(trow * 16 + l15) * 32 + quad * 8];
#pragma unroll
        for (int j = 0; j < 2; j++) {
            bf16x8 b = *(const bf16x8*)&WbaT[(long)((ctile + j) * 16 + l15) * 2048 + k0 + quad * 8];
            acc[j] = MFMA16(a, b, acc[j]);
        }
        __syncthreads();
    }
#pragma unroll
    for (int j = 0; j < 2; j++)
#pragma unroll
        for (int r = 0; r < 4; r++) {
            int tok = m0 + trow * 16 + quad * 4 + r;
            int col = (ctile + j) * 16 + l15;
            float tot = acc[j][r];
            if (col < 32) {
                beta[(long)tok * 32 + col] = 1.f / (1.f + expf(-tot));
            } else {
                int h = col - 32;
                float x = tot + dt_bias[h];
                float sp = (x > 20.f) ? x : log1pf(expf(x));
                g[(long)tok * 32 + h] = -expf(A_log[h]) * sp;
            }
        }
}

// ---------------- causal conv + SiLU + l2norm + split (vectorized) ----------------
__global__ __launch_bounds__(256) void conv_gate(const u16* __restrict__ qkv,
                                                 const float* __restrict__ conv_w,
                                                 u16* __restrict__ qn, u16* __restrict__ kn,
                                                 u16* __restrict__ vc) {
    int tok = blockIdx.x, tid = threadIdx.x;
    int tloc = tok & (T_SEQ - 1);
    __shared__ float mixed[8192];
    __shared__ float sh_norm[32];
    uint4 zero4;
    zero4.x = zero4.y = zero4.z = zero4.w = 0u;
#pragma unroll
    for (int i = 0; i < 4; i++) {
        int c = (i * 256 + tid) * 8;
        long base = (long)tok * 8192 + c;
        uint4 x3 = *(const uint4*)&qkv[base];
        uint4 x2 = (tloc >= 1) ? *(const uint4*)&qkv[base - 8192] : zero4;
        uint4 x1 = (tloc >= 2) ? *(const uint4*)&qkv[base - 16384] : zero4;
        uint4 x0 = (tloc >= 3) ? *(const uint4*)&qkv[base - 24576] : zero4;
        const u16* p0 = (const u16*)&x0;
        const u16* p1 = (const u16*)&x1;
        const u16* p2 = (const u16*)&x2;
        const u16* p3 = (const u16*)&x3;
#pragma unroll
        for (int e = 0; e < 8; e++) {
            float4 wv = *(const float4*)&conv_w[(long)(c + e) * 4];
            float a = bf2f(p0[e]) * wv.x + bf2f(p1[e]) * wv.y + bf2f(p2[e]) * wv.z +
                      bf2f(p3[e]) * wv.w;
            mixed[c + e] = a / (1.f + __expf(-a));
        }
    }
    __syncthreads();
    int grp = tid >> 3, sub = tid & 7;
    float ss = 0.f;
#pragma unroll
    for (int e = 0; e < 16; e++) {
        float v = mixed[grp * 128 + sub * 16 + e];
        ss += v * v;
    }
    ss += __shfl_xor(ss, 4, 8);
    ss += __shfl_xor(ss, 2, 8);
    ss += __shfl_xor(ss, 1, 8);
    if (sub == 0) sh_norm[grp] = rsqrtf(ss + 1e-6f);
    __syncthreads();
#pragma unroll
    for (int i = 0; i < 4; i++) {
        int c = (i * 256 + tid) * 8;
        float nf = (c < 2048) ? sh_norm[c >> 7] * 0.08838834764831845f
                              : ((c < 4096) ? sh_norm[c >> 7] : 1.f);
        u16 ob[8];
#pragma unroll
        for (int e = 0; e < 8; e++) ob[e] = f2bf(mixed[c + e] * nf);
        uint4 val = *(uint4*)ob;
        if (c < 2048)
            *(uint4*)&qn[(long)tok * 2048 + c] = val;
        else if (c < 4096)
            *(uint4*)&kn[(long)tok * 2048 + (c - 2048)] = val;
        else
            *(uint4*)&vc[(long)tok * 4096 + (c - 4096)] = val;
    }
}

// ---------------- phase A: per-chunk WY transform ----------------
__global__ __launch_bounds__(256) void phaseA(const u16* __restrict__ qn,
                                              const u16* __restrict__ kn,
                                              const u16* __restrict__ vc,
                                              const float* __restrict__ g,
                                              const float* __restrict__ beta,
                                              u16* __restrict__ Tv_g, u16* __restrict__ Tw_g,
                                              u16* __restrict__ Q2_g, u16* __restrict__ obuf) {
    __shared__ __align__(16) u16 Yrm[64][256];
    __shared__ __align__(16) float BMt[64][64];
    __shared__ __align__(16) u16 kbuf[64][128];
    u16* Lbf = &kbuf[0][0];

    int bid = blockIdx.x;
    int c = bid & 31, h = (bid >> 5) & 31, b = bid >> 10;
    int hk = h >> 1;
    long tokbase = (long)b * T_SEQ + c * 64;
    long cb = (long)bid * 8192;
    int tid = threadIdx.x, lane = tid & 63, w = tid >> 6;
    int quad = lane >> 4, l15 = lane & 15;

    float gl = g[(tokbase + lane) * 32 + h];
    float bl = beta[(tokbase + lane) * 32 + h];
    float cgl = gl;
#pragma unroll
    for (int d = 1; d < 64; d <<= 1) {
        float y = __shfl_up(cgl, d);
        if (lane >= d) cgl += y;
    }
    float wscl = bl * __expf(cgl);
    float eCgl = __expf(cgl);

#pragma unroll
    for (int p = 0; p < 4; p++) {
        int u = p * 256 + tid;
        int row = u >> 4, col8 = (u & 15) * 8;
        *(uint4*)&kbuf[row][col8] = *(const uint4*)&kn[(tokbase + row) * 2048 + hk * 128 + col8];
    }
    __syncthreads();

    {
        f32x4 gk[4];
#pragma unroll
        for (int nj = 0; nj < 4; nj++) gk[nj] = (f32x4){0.f, 0.f, 0.f, 0.f};
#pragma unroll
        for (int kk = 0; kk < 4; kk++) {
            bf16x8 a = *(const bf16x8*)&kbuf[w * 16 + l15][kk * 32 + quad * 8];
#pragma unroll
            for (int nj = 0; nj < 4; nj++) {
                bf16x8 bb = *(const bf16x8*)&kbuf[nj * 16 + l15][kk * 32 + quad * 8];
                gk[nj] = MFMA16(a, bb, gk[nj]);
            }
        }
#pragma unroll
        for (int nj = 0; nj < 4; nj++)
#pragma unroll
            for (int r = 0; r < 4; r++) {
                int i = w * 16 + quad * 4 + r;
                int j = nj * 16 + l15;
                float cgi = __shfl(cgl, i), cgj = __shfl(cgl, j);
                float bi = __shfl(bl, i);
                BMt[j][i] = (j < i) ? bi * gk[nj][r] * __expf(cgi - cgj) : 0.f;
            }
    }
    __syncthreads();

    {
        int col = tid;
        bool isV = col < 128;
        int kcol = col & 127;
        long vbase = tokbase * 4096 + h * 128 + kcol;
        float Yreg[8], acc8[8];
#pragma unroll 1
        for (int bi = 0; bi < 8; ++bi) {
            float vr[8];
            if (isV) {
#pragma unroll
                for (int ii = 0; ii < 8; ii++)
                    vr[ii] = bf2f(vc[vbase + (long)(bi * 8 + ii) * 4096]);
            }
#pragma unroll
            for (int ii = 0; ii < 8; ii++) acc8[ii] = 0.f;
            for (int j = 0; j < bi * 8; ++j) {
                float yv = bf2f(Yrm[j][col]);
                float4 m0 = *(const float4*)&BMt[j][bi * 8];
                float4 m1 = *(const float4*)&BMt[j][bi * 8 + 4];
                acc8[0] += m0.x * yv;
                acc8[1] += m0.y * yv;
                acc8[2] += m0.z * yv;
                acc8[3] += m0.w * yv;
                acc8[4] += m1.x * yv;
                acc8[5] += m1.y * yv;
                acc8[6] += m1.z * yv;
                acc8[7] += m1.w * yv;
            }
#pragma unroll
            for (int ii = 0; ii < 8; ii++) {
                int i = bi * 8 + ii;
                float rhs = isV ? __shfl(bl, i) * vr[ii] : __shfl(wscl, i) * bf2f(kbuf[i][kcol]);
                float s = rhs - acc8[ii];
#pragma unroll
                for (int jj = 0; jj < 8; jj++)
                    if (jj < ii) s -= BMt[bi * 8 + jj][i] * Yreg[jj];
                Yreg[ii] = s;
                u16 sb = f2bf(s);
                Yrm[i][col] = sb;
                if (isV)
                    Tv_g[cb + i * 128 + kcol] = sb;
                else
                    Tw_g[cb + i * 128 + kcol] = sb;
            }
        }
    }
    __syncthreads();

    {
        f32x4 qk_[4];
#pragma unroll
        for (int nj = 0; nj < 4; nj++) qk_[nj] = (f32x4){0.f, 0.f, 0.f, 0.f};
#pragma unroll
        for (int kk = 0; kk < 4; kk++) {
            bf16x8 a = *(const bf16x8*)&qn[(tokbase + w * 16 + l15) * 2048 + hk * 128 + kk * 32 +
                                           quad * 8];
#pragma unroll
            for (int nj = 0; nj < 4; nj++) {
                bf16x8 bb = *(const bf16x8*)&kbuf[nj * 16 + l15][kk * 32 + quad * 8];
                qk_[nj] = MFMA16(a, bb, qk_[nj]);
            }
        }
        __syncthreads();
#pragma unroll
        for (int nj = 0; nj < 4; nj++)
#pragma unroll
            for (int r = 0; r < 4; r++) {
                int t = w * 16 + quad * 4 + r;
                int rr = nj * 16 + l15;
                float cgt = __shfl(cgl, t), cgr = __shfl(cgl, rr);
                float val = (rr <= t) ? qk_[nj][r] * __expf(cgt - cgr) : 0.f;
                Lbf[t * 64 + rr] = f2bf(val);
            }
    }
    __syncthreads();

#pragma unroll 1
    for (int half = 0; half < 2; half++) {
        f32x4 oa[8];
#pragma unroll
        for (int nj = 0; nj < 8; nj++) oa[nj] = (f32x4){0.f, 0.f, 0.f, 0.f};
#pragma unroll
        for (int kk = 0; kk < 2; kk++) {
            bf16x8 a = *(const bf16x8*)&Lbf[(w * 16 + l15) * 64 + kk * 32 + quad * 8];
#pragma unroll
            for (int nj = 0; nj < 8; nj++) {
                bf16x8 bb;
#pragma unroll
                for (int jj = 0; jj < 8; jj++)
                    bb[jj] = (short)Yrm[kk * 32 + quad * 8 + jj][half * 128 + nj * 16 + l15];
                oa[nj] = MFMA16(a, bb, oa[nj]);
            }
        }
        if (half == 0) {
#pragma unroll
            for (int nj = 0; nj < 8; nj++)
#pragma unroll
                for (int r = 0; r < 4; r++) {
                    int t = w * 16 + quad * 4 + r;
                    int vcol = nj * 16 + l15;
                    obuf[(tokbase + t) * 4096 + h * 128 + vcol] = f2bf(oa[nj][r]);
                }
        } else {
#pragma unroll
            for (int nj = 0; nj < 8; nj++)
#pragma unroll
                for (int r = 0; r < 4; r++) {
                    int t = w * 16 + quad * 4 + r;
                    int kcol = nj * 16 + l15;
                    float qsc = __shfl(eCgl, t);
                    float qv = bf2f(qn[(tokbase + t) * 2048 + hk * 128 + kcol]);
                    Q2_g[cb + t * 128 + kcol] = f2bf(qsc * qv - oa[nj][r]);
                }
        }
    }
}

// ---------------- phase B: sequential chunk recurrence (32 steps) ----------------
__global__ __launch_bounds__(256) void phaseB(const u16* __restrict__ kn,
                                              const float* __restrict__ g,
                                              const u16* __restrict__ Tv_g,
                                              const u16* __restrict__ Tw_g,
                                              const u16* __restrict__ Q2_g,
                                              u16* __restrict__ obuf) {
    __shared__ __align__(16) float Sf[128][32];
    __shared__ __align__(16) u16 SbfT[32][128];
    __shared__ __align__(16) u16 KhT[128][64];
    __shared__ __align__(16) u16 Ut[32][64];

    int bid = blockIdx.x;
    int vq = bid & 3, h = (bid >> 2) & 31, b = bid >> 7;
    int hk = h >> 1;
    int tid = threadIdx.x, lane = tid & 63, w = tid >> 6;
    int quad = lane >> 4, l15 = lane & 15;

    for (int p = tid; p < 128 * 32; p += 256) {
        ((float*)Sf)[p] = 0.f;
        ((u16*)SbfT)[p] = 0;
    }
    __syncthreads();

    for (int c = 0; c < 32; ++c) {
        long tokbase = (long)b * T_SEQ + c * 64;
        long cb = (long)(((b * 32 + h) * 32) + c) * 8192;
        float gl = g[(tokbase + lane) * 32 + h];
        float cgl = gl;
#pragma unroll
        for (int d = 1; d < 64; d <<= 1) {
            float y = __shfl_up(cgl, d);
            if (lane >= d) cgl += y;
        }
        float cgC = __shfl(cgl, 63);
        float A_C = __expf(cgC);
        float kscl = __expf(cgC - cgl);

        {
            int s = tid >> 2, qq = tid & 3;
            float ksc = __shfl(kscl, s);
            const u16* kp = &kn[(tokbase + s) * 2048 + hk * 128 + qq * 32];
            u16 tmp[32];
            *(uint4*)&tmp[0] = *(const uint4*)&kp[0];
            *(uint4*)&tmp[8] = *(const uint4*)&kp[8];
            *(uint4*)&tmp[16] = *(const uint4*)&kp[16];
            *(uint4*)&tmp[24] = *(const uint4*)&kp[24];
#pragma unroll
            for (int j = 0; j < 32; j++) KhT[qq * 32 + j][s] = f2bf(bf2f(tmp[j]) * ksc);
        }

        f32x4 y1[2], oo[2];
#pragma unroll
        for (int nj = 0; nj < 2; nj++) {
            y1[nj] = (f32x4){0.f, 0.f, 0.f, 0.f};
            oo[nj] = (f32x4){0.f, 0.f, 0.f, 0.f};
        }
#pragma unroll
        for (int kk = 0; kk < 4; kk++) {
            bf16x8 aTw = *(const bf16x8*)&Tw_g[cb + (w * 16 + l15) * 128 + kk * 32 + quad * 8];
            bf16x8 aQ2 = *(const bf16x8*)&Q2_g[cb + (w * 16 + l15) * 128 + kk * 32 + quad * 8];
#pragma unroll
            for (int nj = 0; nj < 2; nj++) {
                bf16x8 bb = *(const bf16x8*)&SbfT[nj * 16 + l15][kk * 32 + quad * 8];
                y1[nj] = MFMA16(aTw, bb, y1[nj]);
                oo[nj] = MFMA16(aQ2, bb, oo[nj]);
            }
        }
#pragma unroll
        for (int nj = 0; nj < 2; nj++)
#pragma unroll
            for (int r = 0; r < 4; r++) {
                int i = w * 16 + quad * 4 + r;
                int vl = nj * 16 + l15;
                int vg = vq * 32 + vl;
                float tvv = bf2f(Tv_g[cb + (long)i * 128 + vg]);
                Ut[vl][i] = f2bf(tvv - y1[nj][r]);
                long op = (tokbase + i) * 4096 + h * 128 + vg;
                obuf[op] = f2bf(bf2f(obuf[op]) + oo[nj][r]);
            }
        __syncthreads();

#pragma unroll
        for (int mm = 0; mm < 2; mm++) {
            int mi = 2 * w + mm;
#pragma unroll
            for (int nj = 0; nj < 2; nj++) {
                f32x4 sacc;
#pragma unroll
                for (int r = 0; r < 4; r++)
                    sacc[r] = A_C * Sf[mi * 16 + quad * 4 + r][nj * 16 + l15];
#pragma unroll
                for (int kk = 0; kk < 2; kk++) {
                    bf16x8 a = *(const bf16x8*)&KhT[mi * 16 + l15][kk * 32 + quad * 8];
                    bf16x8 bb = *(const bf16x8*)&Ut[nj * 16 + l15][kk * 32 + quad * 8];
                    sacc = MFMA16(a, bb, sacc);
                }
#pragma unroll
                for (int r = 0; r < 4; r++) {
                    int kd = mi * 16 + quad * 4 + r, vl = nj * 16 + l15;
                    Sf[kd][vl] = sacc[r];
                    SbfT[vl][kd] = f2bf(sacc[r]);
                }
            }
        }
        __syncthreads();
    }
}

// ---------------- gated RMSNorm ----------------
__global__ __launch_bounds__(256) void gated_norm(const u16* __restrict__ obuf,
                                                  const u16* __restrict__ zbuf,
                                                  const float* __restrict__ norm_w,
                                                  u16* __restrict__ xn) {
    int tok = blockIdx.x, tid = threadIdx.x;
    long obase = (long)tok * 4096 + tid * 16;
    u16 ob[16], zb[16];
    *(uint4*)(ob + 0) = *(const uint4*)&obuf[obase];
    *(uint4*)(ob + 8) = *(const uint4*)&obuf[obase + 8];
    *(uint4*)(zb + 0) = *(const uint4*)&zbuf[obase];
    *(uint4*)(zb + 8) = *(const uint4*)&zbuf[obase + 8];
    float x[16];
    float ss = 0.f;
#pragma unroll
    for (int i = 0; i < 16; i++) {
        float ov = bf2f(ob[i]);
        float zv = bf2f(zb[i]);
        float xv = ov * (zv / (1.f + expf(-zv)));
        x[i] = xv;
        ss += xv * xv;
    }
    ss += __shfl_xor(ss, 4, 8);
    ss += __shfl_xor(ss, 2, 8);
    ss += __shfl_xor(ss, 1, 8);
    float scale = rsqrtf(ss * (1.f / 128.f) + 1e-6f);
    int cbase = (tid * 16) & 127;
#pragma unroll
    for (int i = 0; i < 16; i++)
        xn[(long)tok * 4096 + tid * 16 + i] = f2bf(x[i] * scale * (1.f + norm_w[cbase + i]));
}

// ---------------- launch ----------------
extern "C" void kernel_launch(void* const* d_in, const int* in_sizes, int n_in, void* d_out,
                              int out_size, void* d_ws, size_t ws_size, hipStream_t stream) {
    const float* hidden = (const float*)d_in[0];
    const float* W_qkvz = (const float*)d_in[1];
    const float* W_ba = (const float*)d_in[2];
    const float* conv_w = (const float*)d_in[3];
    const float* A_log = (const float*)d_in[4];
    const float* dt_bias = (const float*)d_in[5];
    const float* norm_w = (const float*)d_in[6];
    const float* W_out = (const float*)d_in[7];
    float* out = (float*)d_out;

    char* ws = (char*)d_ws;
    // [0,        50331648)  wqT            -> later qn@0, vc/obuf@16777216
    // [50331648, 67108864)  hidbf          -> later kn
    // [67108864, 83886080)  woT            (persistent)
    // [83886080, 150994944) qkv_raw        -> later Tv@83886080, Tw@117440512 -> later xn
    // [150994944,184549376) W_baT (temp, 256KB) then zbuf (persistent)
    // [184549376,218103808) Q2
    // [218103808,218628096) g
    // [218628096,219152384) beta
    u16* wqT = (u16*)(ws + 0);
    u16* qn = (u16*)(ws + 0);
    u16* vc = (u16*)(ws + 16777216L);
    u16* hidbf = (u16*)(ws + 50331648L);
    u16* kn = (u16*)(ws + 50331648L);
    u16* woT = (u16*)(ws + 67108864L);
    u16* qkv_raw = (u16*)(ws + 83886080L);
    u16* Tv = (u16*)(ws + 83886080L);
    u16* Tw = (u16*)(ws + 117440512L);
    u16* xn = (u16*)(ws + 83886080L);
    u16* WbaT = (u16*)(ws + 150994944L);
    u16* zbuf = (u16*)(ws + 150994944L);
    u16* Q2 = (u16*)(ws + 184549376L);
    float* g = (float*)(ws + 218103808L);
    float* beta = (float*)(ws + 218628096L);
    u16* obuf = vc;

    cast_f32_bf16<<<8192, 256, 0, stream>>>(hidden, hidbf, 8388608L);
    transpose_cast<<<dim3(384, 64), 256, 0, stream>>>(W_qkvz, wqT, 2048, 12288);
    transpose_cast<<<dim3(64, 128), 256, 0, stream>>>(W_out, woT, 4096, 2048);
    transpose_cast<<<dim3(2, 64), 256, 0, stream>>>(W_ba, WbaT, 2048, 64);
    ba_gemm<<<128, 256, 0, stream>>>(hidbf, WbaT, A_log, dt_bias, g, beta);
    gemm_bt<2><<<dim3(32, 96), 256, 0, stream>>>(hidbf, wqT, qkv_raw, zbuf, 4096, 12288, 2048,
                                                 2048, 2048, 0);
    conv_gate<<<4096, 256, 0, stream>>>(qkv_raw, conv_w, qn, kn, vc);
    phaseA<<<2048, 256, 0, stream>>>(qn, kn, vc, g, beta, Tv, Tw, Q2, obuf);
    phaseB<<<256, 256, 0, stream>>>(kn, g, Tv, Tw, Q2, obuf);
    gated_norm<<<4096, 256, 0, stream>>>(obuf, zbuf, norm_w, xn);
    gemm_bt<0><<<dim3(32, 16), 256, 0, stream>>>(xn, woT, out, nullptr, 4096, 2048, 4096, 4096,
                                                 4096, 2048);
}

// Round 4
// 1037.953 us; speedup vs baseline: 2.6575x; 1.0792x over previous
//
#include <hip/hip_runtime.h>

typedef unsigned short u16;
typedef unsigned int u32;

typedef short bf16x8 __attribute__((ext_vector_type(8)));
typedef float f32x4 __attribute__((ext_vector_type(4)));
typedef float f32x16 __attribute__((ext_vector_type(16)));

#define T_SEQ 2048
#define MFMA16(a, b, c) __builtin_amdgcn_mfma_f32_16x16x32_bf16(a, b, c, 0, 0, 0)
#define MFMA32(a, b, c) __builtin_amdgcn_mfma_f32_32x32x16_bf16(a, b, c, 0, 0, 0)

__device__ __forceinline__ u16 f2bf(float f) {
    u32 u = __float_as_uint(f);
    u += 0x7fffu + ((u >> 16) & 1u);
    return (u16)(u >> 16);
}
__device__ __forceinline__ float bf2f(u16 s) {
    return __uint_as_float(((u32)s) << 16);
}
__device__ __forceinline__ void g2lds16(const u16* gp, u16* lp) {
    __builtin_amdgcn_global_load_lds((const __attribute__((address_space(1))) void*)gp,
                                     (__attribute__((address_space(3))) void*)lp, 16, 0, 0);
}

// ---------------- cast fp32 -> bf16 ----------------
__global__ __launch_bounds__(256) void cast_f32_bf16(const float* __restrict__ in,
                                                     u16* __restrict__ out, long n) {
    long i = ((long)blockIdx.x * 256 + threadIdx.x) * 4;
    if (i + 3 < n) {
        float4 v = *(const float4*)&in[i];
        out[i + 0] = f2bf(v.x);
        out[i + 1] = f2bf(v.y);
        out[i + 2] = f2bf(v.z);
        out[i + 3] = f2bf(v.w);
    }
}

// ---------------- transpose + cast: [R,C] f32 -> [C,R] bf16 ----------------
__global__ __launch_bounds__(256) void transpose_cast(const float* __restrict__ in,
                                                      u16* __restrict__ out, int R, int C) {
    __shared__ float tile[32][33];
    int c0 = blockIdx.x * 32, r0 = blockIdx.y * 32;
    int tx = threadIdx.x & 31, ty = threadIdx.x >> 5;
#pragma unroll
    for (int rr = 0; rr < 32; rr += 8)
        tile[ty + rr][tx] = in[(long)(r0 + ty + rr) * C + c0 + tx];
    __syncthreads();
#pragma unroll
    for (int rr = 0; rr < 32; rr += 8)
        out[(long)(c0 + ty + rr) * R + r0 + tx] = f2bf(tile[tx][ty + rr]);
}

// ---------------- GEMM: C[M,N] = A[M,K] * BT[N,K], 32x32x16 MFMA ----------------
// MODE 0: f32 out ; MODE 2: split bf16 qkv(cols<8192, ld 8192)/z(ld 4096)
template <int MODE>
__global__ __launch_bounds__(256) void gemm_bt(const u16* __restrict__ A,
                                               const u16* __restrict__ B, void* __restrict__ C,
                                               void* __restrict__ C2, int M, int N, int K, int lda,
                                               int ldb, int ldc) {
    __shared__ __align__(16) u16 As[128 * 32];
    __shared__ __align__(16) u16 Bs[128 * 32];
    int m0 = blockIdx.x * 128, n0 = blockIdx.y * 128;
    int tid = threadIdx.x;
    int lane = tid & 63, w = tid >> 6;
    int wr = w >> 1, wc = w & 1;
    int l31 = lane & 31, hf = lane >> 5;

    f32x16 acc[2][2];
#pragma unroll
    for (int mi = 0; mi < 2; mi++)
#pragma unroll
        for (int nj = 0; nj < 2; nj++)
#pragma unroll
            for (int r = 0; r < 16; r++) acc[mi][nj][r] = 0.f;

    int srow = tid >> 2, sc8 = (tid & 3) * 8;
    const u16* Ag = &A[(long)(m0 + srow) * lda + sc8];
    const u16* Bg = &B[(long)(n0 + srow) * ldb + sc8];

    for (int k0 = 0; k0 < K; k0 += 32) {
        g2lds16(Ag + k0, &As[tid * 8]);
        g2lds16(Ag + (long)64 * lda + k0, &As[(256 + tid) * 8]);
        g2lds16(Bg + k0, &Bs[tid * 8]);
        g2lds16(Bg + (long)64 * ldb + k0, &Bs[(256 + tid) * 8]);
        __syncthreads();
        bf16x8 af[2][2], bfr[2][2];
#pragma unroll
        for (int mi = 0; mi < 2; mi++)
#pragma unroll
            for (int ks = 0; ks < 2; ks++) {
                af[mi][ks] = *(const bf16x8*)&As[(wr * 64 + mi * 32 + l31) * 32 + ks * 16 + hf * 8];
                bfr[mi][ks] =
                    *(const bf16x8*)&Bs[(wc * 64 + mi * 32 + l31) * 32 + ks * 16 + hf * 8];
            }
#pragma unroll
        for (int ks = 0; ks < 2; ks++)
#pragma unroll
            for (int mi = 0; mi < 2; mi++)
#pragma unroll
                for (int nj = 0; nj < 2; nj++)
                    acc[mi][nj] = MFMA32(af[mi][ks], bfr[nj][ks], acc[mi][nj]);
        __syncthreads();
    }

    if (MODE == 0) {
#pragma unroll
        for (int mi = 0; mi < 2; mi++)
#pragma unroll
            for (int nj = 0; nj < 2; nj++)
#pragma unroll
                for (int r = 0; r < 16; r++) {
                    int row = m0 + wr * 64 + mi * 32 + (r >> 2) * 8 + hf * 4 + (r & 3);
                    int col = n0 + wc * 64 + nj * 32 + l31;
                    ((float*)C)[(long)row * ldc + col] = acc[mi][nj][r];
                }
    } else {
        u16* dst;
        long dldc;
        int ncol0;
        if (MODE == 2 && n0 >= 8192) {
            dst = (u16*)C2;
            dldc = 4096;
            ncol0 = n0 - 8192;
        } else {
            dst = (u16*)C;
            dldc = (MODE == 2) ? 8192 : ldc;
            ncol0 = n0;
        }
#pragma unroll 1
        for (int half_e = 0; half_e < 2; half_e++) {
            __syncthreads();
            if (wc == half_e) {
#pragma unroll
                for (int mi = 0; mi < 2; mi++)
#pragma unroll
                    for (int nj = 0; nj < 2; nj++)
#pragma unroll
                        for (int r = 0; r < 16; r++) {
                            int row = wr * 64 + mi * 32 + (r >> 2) * 8 + hf * 4 + (r & 3);
                            int col = nj * 32 + l31;
                            u16* base = (row < 64) ? As : Bs;
                            base[(row & 63) * 64 + col] = f2bf(acc[mi][nj][r]);
                        }
            }
            __syncthreads();
#pragma unroll
            for (int rr = 0; rr < 4; rr++) {
                int row = rr * 32 + (tid >> 3), seg = tid & 7;
                u16* base = (row < 64) ? As : Bs;
                *(uint4*)&dst[(long)(m0 + row) * dldc + ncol0 + half_e * 64 + seg * 8] =
                    *(uint4*)&base[(row & 63) * 64 + seg * 8];
            }
        }
    }
}

// ---------------- ba = hidden @ W_ba -> g, beta (MFMA + LDS-staged W) ----------------
__global__ __launch_bounds__(256) void ba_gemm(const u16* __restrict__ hid,
                                               const u16* __restrict__ WbaT,
                                               const float* __restrict__ A_log,
                                               const float* __restrict__ dt_bias,
                                               float* __restrict__ g, float* __restrict__ beta) {
    __shared__ __align__(16) u16 As2[32 * 32];
    __shared__ __align__(16) u16 Bs2[64 * 32];
    int m0 = blockIdx.x * 32;
    int tid = threadIdx.x, lane = tid & 63, w = tid >> 6;
    int quad = lane >> 4, l15 = lane & 15;
    int trow = w & 1;
    int ctile = (w >> 1) * 2;
    f32x4 acc[2];
    acc[0] = (f32x4){0.f, 0.f, 0.f, 0.f};
    acc[1] = (f32x4){0.f, 0.f, 0.f, 0.f};
    int srow = tid >> 2, sc8 = (tid & 3) * 8;
    for (int k0 = 0; k0 < 2048; k0 += 32) {
        if (tid < 128)
            *(uint4*)&As2[srow * 32 + sc8] = *(const uint4*)&hid[(long)(m0 + srow) * 2048 + k0 + sc8];
        *(uint4*)&Bs2[srow * 32 + sc8] = *(const uint4*)&WbaT[(long)srow * 2048 + k0 + sc8];
        __syncthreads();
        bf16x8 a = *(const bf16x8*)&As2[(trow * 16 + l15) * 32 + quad * 8];
#pragma unroll
        for (int j = 0; j < 2; j++) {
            bf16x8 b = *(const bf16x8*)&Bs2[((ctile + j) * 16 + l15) * 32 + quad * 8];
            acc[j] = MFMA16(a, b, acc[j]);
        }
        __syncthreads();
    }
#pragma unroll
    for (int j = 0; j < 2; j++)
#pragma unroll
        for (int r = 0; r < 4; r++) {
            int tok = m0 + trow * 16 + quad * 4 + r;
            int col = (ctile + j) * 16 + l15;
            float tot = acc[j][r];
            if (col < 32) {
                beta[(long)tok * 32 + col] = 1.f / (1.f + expf(-tot));
            } else {
                int h = col - 32;
                float x = tot + dt_bias[h];
                float sp = (x > 20.f) ? x : log1pf(expf(x));
                g[(long)tok * 32 + h] = -expf(A_log[h]) * sp;
            }
        }
}

// ---------------- causal conv + SiLU + l2norm + split ----------------
__global__ __launch_bounds__(256) void conv_gate(const u16* __restrict__ qkv,
                                                 const float* __restrict__ conv_w,
                                                 u16* __restrict__ qn, u16* __restrict__ kn,
                                                 u16* __restrict__ vc) {
    int tok = blockIdx.x, tid = threadIdx.x;
    int tloc = tok & (T_SEQ - 1);
    __shared__ float mixed[8192];
    __shared__ float sh_norm[32];
    uint4 zero4;
    zero4.x = zero4.y = zero4.z = zero4.w = 0u;
#pragma unroll
    for (int i = 0; i < 4; i++) {
        int c = (i * 256 + tid) * 8;
        long base = (long)tok * 8192 + c;
        uint4 x3 = *(const uint4*)&qkv[base];
        uint4 x2 = (tloc >= 1) ? *(const uint4*)&qkv[base - 8192] : zero4;
        uint4 x1 = (tloc >= 2) ? *(const uint4*)&qkv[base - 16384] : zero4;
        uint4 x0 = (tloc >= 3) ? *(const uint4*)&qkv[base - 24576] : zero4;
        const u16* p0 = (const u16*)&x0;
        const u16* p1 = (const u16*)&x1;
        const u16* p2 = (const u16*)&x2;
        const u16* p3 = (const u16*)&x3;
#pragma unroll
        for (int e = 0; e < 8; e++) {
            float4 wv = *(const float4*)&conv_w[(long)(c + e) * 4];
            float a = bf2f(p0[e]) * wv.x + bf2f(p1[e]) * wv.y + bf2f(p2[e]) * wv.z +
                      bf2f(p3[e]) * wv.w;
            mixed[c + e] = a / (1.f + __expf(-a));
        }
    }
    __syncthreads();
    int grp = tid >> 3, sub = tid & 7;
    float ss = 0.f;
#pragma unroll
    for (int e = 0; e < 16; e++) {
        float v = mixed[grp * 128 + sub * 16 + e];
        ss += v * v;
    }
    ss += __shfl_xor(ss, 4, 8);
    ss += __shfl_xor(ss, 2, 8);
    ss += __shfl_xor(ss, 1, 8);
    if (sub == 0) sh_norm[grp] = rsqrtf(ss + 1e-6f);
    __syncthreads();
#pragma unroll
    for (int i = 0; i < 4; i++) {
        int c = (i * 256 + tid) * 8;
        float nf = (c < 2048) ? sh_norm[c >> 7] * 0.08838834764831845f
                              : ((c < 4096) ? sh_norm[c >> 7] : 1.f);
        u16 ob[8];
#pragma unroll
        for (int e = 0; e < 8; e++) ob[e] = f2bf(mixed[c + e] * nf);
        uint4 val = *(uint4*)ob;
        if (c < 2048)
            *(uint4*)&qn[(long)tok * 2048 + c] = val;
        else if (c < 4096)
            *(uint4*)&kn[(long)tok * 2048 + (c - 2048)] = val;
        else
            *(uint4*)&vc[(long)tok * 4096 + (c - 4096)] = val;
    }
}

// ---------------- phase A: per-chunk WY transform ----------------
__global__ __launch_bounds__(256) void phaseA(const u16* __restrict__ qn,
                                              const u16* __restrict__ kn,
                                              const u16* __restrict__ vc,
                                              const float* __restrict__ g,
                                              const float* __restrict__ beta,
                                              u16* __restrict__ Tv_g, u16* __restrict__ Tw_g,
                                              u16* __restrict__ Q2_g, u16* __restrict__ obuf) {
    __shared__ __align__(16) u16 Yrm[64][256];
    __shared__ __align__(16) float BMt[64][64];
    __shared__ __align__(16) u16 kbuf[64][128];
    u16* Lbf = &kbuf[0][0];

    int bid = blockIdx.x;
    int c = bid & 31, h = (bid >> 5) & 31, b = bid >> 10;
    int hk = h >> 1;
    long tokbase = (long)b * T_SEQ + c * 64;
    long cb = (long)bid * 8192;
    int tid = threadIdx.x, lane = tid & 63, w = tid >> 6;
    int quad = lane >> 4, l15 = lane & 15;

    float gl = g[(tokbase + lane) * 32 + h];
    float bl = beta[(tokbase + lane) * 32 + h];
    float cgl = gl;
#pragma unroll
    for (int d = 1; d < 64; d <<= 1) {
        float y = __shfl_up(cgl, d);
        if (lane >= d) cgl += y;
    }
    float wscl = bl * __expf(cgl);
    float eCgl = __expf(cgl);

#pragma unroll
    for (int p = 0; p < 4; p++) {
        int u = p * 256 + tid;
        int row = u >> 4, col8 = (u & 15) * 8;
        *(uint4*)&kbuf[row][col8] = *(const uint4*)&kn[(tokbase + row) * 2048 + hk * 128 + col8];
    }
    __syncthreads();

    {
        f32x4 gk[4];
#pragma unroll
        for (int nj = 0; nj < 4; nj++) gk[nj] = (f32x4){0.f, 0.f, 0.f, 0.f};
#pragma unroll
        for (int kk = 0; kk < 4; kk++) {
            bf16x8 a = *(const bf16x8*)&kbuf[w * 16 + l15][kk * 32 + quad * 8];
#pragma unroll
            for (int nj = 0; nj < 4; nj++) {
                bf16x8 bb = *(const bf16x8*)&kbuf[nj * 16 + l15][kk * 32 + quad * 8];
                gk[nj] = MFMA16(a, bb, gk[nj]);
            }
        }
#pragma unroll
        for (int nj = 0; nj < 4; nj++)
#pragma unroll
            for (int r = 0; r < 4; r++) {
                int i = w * 16 + quad * 4 + r;
                int j = nj * 16 + l15;
                float cgi = __shfl(cgl, i), cgj = __shfl(cgl, j);
                float bi = __shfl(bl, i);
                BMt[j][i] = (j < i) ? bi * gk[nj][r] * __expf(cgi - cgj) : 0.f;
            }
    }
    __syncthreads();

    {
        int col = tid;
        bool isV = col < 128;
        int kcol = col & 127;
        long vbase = tokbase * 4096 + h * 128 + kcol;
        float Yreg[8], acc8[8];
#pragma unroll 1
        for (int bi = 0; bi < 8; ++bi) {
            float vr[8];
            if (isV) {
#pragma unroll
                for (int ii = 0; ii < 8; ii++)
                    vr[ii] = bf2f(vc[vbase + (long)(bi * 8 + ii) * 4096]);
            }
#pragma unroll
            for (int ii = 0; ii < 8; ii++) acc8[ii] = 0.f;
            for (int j = 0; j < bi * 8; ++j) {
                float yv = bf2f(Yrm[j][col]);
                float4 m0 = *(const float4*)&BMt[j][bi * 8];
                float4 m1 = *(const float4*)&BMt[j][bi * 8 + 4];
                acc8[0] += m0.x * yv;
                acc8[1] += m0.y * yv;
                acc8[2] += m0.z * yv;
                acc8[3] += m0.w * yv;
                acc8[4] += m1.x * yv;
                acc8[5] += m1.y * yv;
                acc8[6] += m1.z * yv;
                acc8[7] += m1.w * yv;
            }
#pragma unroll
            for (int ii = 0; ii < 8; ii++) {
                int i = bi * 8 + ii;
                float rhs = isV ? __shfl(bl, i) * vr[ii] : __shfl(wscl, i) * bf2f(kbuf[i][kcol]);
                float s = rhs - acc8[ii];
#pragma unroll
                for (int jj = 0; jj < 8; jj++)
                    if (jj < ii) s -= BMt[bi * 8 + jj][i] * Yreg[jj];
                Yreg[ii] = s;
                u16 sb = f2bf(s);
                Yrm[i][col] = sb;
                if (isV)
                    Tv_g[cb + i * 128 + kcol] = sb;
                else
                    Tw_g[cb + i * 128 + kcol] = sb;
            }
        }
    }
    __syncthreads();

    {
        f32x4 qk_[4];
#pragma unroll
        for (int nj = 0; nj < 4; nj++) qk_[nj] = (f32x4){0.f, 0.f, 0.f, 0.f};
#pragma unroll
        for (int kk = 0; kk < 4; kk++) {
            bf16x8 a = *(const bf16x8*)&qn[(tokbase + w * 16 + l15) * 2048 + hk * 128 + kk * 32 +
                                           quad * 8];
#pragma unroll
            for (int nj = 0; nj < 4; nj++) {
                bf16x8 bb = *(const bf16x8*)&kbuf[nj * 16 + l15][kk * 32 + quad * 8];
                qk_[nj] = MFMA16(a, bb, qk_[nj]);
            }
        }
        __syncthreads();
#pragma unroll
        for (int nj = 0; nj < 4; nj++)
#pragma unroll
            for (int r = 0; r < 4; r++) {
                int t = w * 16 + quad * 4 + r;
                int rr = nj * 16 + l15;
                float cgt = __shfl(cgl, t), cgr = __shfl(cgl, rr);
                float val = (rr <= t) ? qk_[nj][r] * __expf(cgt - cgr) : 0.f;
                Lbf[t * 64 + rr] = f2bf(val);
            }
    }
    __syncthreads();

#pragma unroll 1
    for (int half = 0; half < 2; half++) {
        f32x4 oa[8];
#pragma unroll
        for (int nj = 0; nj < 8; nj++) oa[nj] = (f32x4){0.f, 0.f, 0.f, 0.f};
#pragma unroll
        for (int kk = 0; kk < 2; kk++) {
            bf16x8 a = *(const bf16x8*)&Lbf[(w * 16 + l15) * 64 + kk * 32 + quad * 8];
#pragma unroll
            for (int nj = 0; nj < 8; nj++) {
                bf16x8 bb;
#pragma unroll
                for (int jj = 0; jj < 8; jj++)
                    bb[jj] = (short)Yrm[kk * 32 + quad * 8 + jj][half * 128 + nj * 16 + l15];
                oa[nj] = MFMA16(a, bb, oa[nj]);
            }
        }
        if (half == 0) {
#pragma unroll
            for (int nj = 0; nj < 8; nj++)
#pragma unroll
                for (int r = 0; r < 4; r++) {
                    int t = w * 16 + quad * 4 + r;
                    int vcol = nj * 16 + l15;
                    obuf[(tokbase + t) * 4096 + h * 128 + vcol] = f2bf(oa[nj][r]);
                }
        } else {
#pragma unroll
            for (int nj = 0; nj < 8; nj++)
#pragma unroll
                for (int r = 0; r < 4; r++) {
                    int t = w * 16 + quad * 4 + r;
                    int kcol = nj * 16 + l15;
                    float qsc = __shfl(eCgl, t);
                    float qv = bf2f(qn[(tokbase + t) * 2048 + hk * 128 + kcol]);
                    Q2_g[cb + t * 128 + kcol] = f2bf(qsc * qv - oa[nj][r]);
                }
        }
    }
}

// ---------------- phase B: sequential chunk recurrence, software-pipelined ----------------
__global__ __launch_bounds__(256) void phaseB(const u16* __restrict__ kn,
                                              const float* __restrict__ g,
                                              const u16* __restrict__ Tv_g,
                                              const u16* __restrict__ Tw_g,
                                              const u16* __restrict__ Q2_g,
                                              u16* __restrict__ obuf) {
    __shared__ __align__(16) float Sf[128][32];   // 16 KB
    __shared__ __align__(16) u16 SbfT[32][136];   // padded, rows 272B (16B-aligned)
    __shared__ __align__(16) u16 KhT[128][72];    // padded, rows 144B
    __shared__ __align__(16) u16 Ut[32][72];      // padded, rows 144B

    int bid = blockIdx.x;
    int vq = bid & 3, h = (bid >> 2) & 31, b = bid >> 7;
    int hk = h >> 1;
    int tid = threadIdx.x, lane = tid & 63, w = tid >> 6;
    int quad = lane >> 4, l15 = lane & 15;

    for (int p = tid; p < 128 * 32; p += 256) ((float*)Sf)[p] = 0.f;
    for (int p = tid; p < 32 * 136; p += 256) ((u16*)SbfT)[p] = 0;
    __syncthreads();

    // prefetch registers for step c
    float gl_pf;
    uint4 kreg[4];
    bf16x8 aTw[4], aQ2[4];
    u16 tvv_pf[2][4], oold[2][4];

#define PB_PREFETCH(cc)                                                                      \
    {                                                                                        \
        long tb_ = (long)b * T_SEQ + (cc) * 64;                                              \
        long cb_ = ((long)((b * 32 + h) * 32) + (cc)) * 8192;                                \
        gl_pf = g[(tb_ + lane) * 32 + h];                                                    \
        const u16* kp_ = &kn[(tb_ + lane) * 2048 + hk * 128 + w * 32];                       \
        kreg[0] = *(const uint4*)&kp_[0];                                                    \
        kreg[1] = *(const uint4*)&kp_[8];                                                    \
        kreg[2] = *(const uint4*)&kp_[16];                                                   \
        kreg[3] = *(const uint4*)&kp_[24];                                                   \
        _Pragma("unroll") for (int kk = 0; kk < 4; kk++) {                                   \
            aTw[kk] = *(const bf16x8*)&Tw_g[cb_ + (w * 16 + l15) * 128 + kk * 32 + quad * 8]; \
            aQ2[kk] = *(const bf16x8*)&Q2_g[cb_ + (w * 16 + l15) * 128 + kk * 32 + quad * 8]; \
        }                                                                                    \
        _Pragma("unroll") for (int nj = 0; nj < 2; nj++) _Pragma("unroll")                   \
            for (int r = 0; r < 4; r++) {                                                    \
            int i_ = w * 16 + quad * 4 + r;                                                  \
            int vg_ = vq * 32 + nj * 16 + l15;                                               \
            tvv_pf[nj][r] = Tv_g[cb_ + (long)i_ * 128 + vg_];                                \
            oold[nj][r] = obuf[(tb_ + i_) * 4096 + h * 128 + vg_];                           \
        }                                                                                    \
    }

    PB_PREFETCH(0);

    for (int c = 0; c < 32; ++c) {
        long tokbase = (long)b * T_SEQ + c * 64;
        // decay scan (uses gl_pf)
        float cgl = gl_pf;
#pragma unroll
        for (int d = 1; d < 64; d <<= 1) {
            float y = __shfl_up(cgl, d);
            if (lane >= d) cgl += y;
        }
        float cgC = __shfl(cgl, 63);
        float A_C = __expf(cgC);
        float kscl = __expf(cgC - cgl);

        // KhT[kdim = w*32+j][s = lane] = exp(cgC - cg_s) * k[s][kdim]  (uses kreg)
        {
            const u16* kk16 = (const u16*)kreg;
#pragma unroll
            for (int j = 0; j < 32; j++) KhT[w * 32 + j][lane] = f2bf(bf2f(kk16[j]) * kscl);
        }

        // group 1: Y1 = Tw*S0 ; O = Q2*S0 (uses aTw/aQ2 + SbfT)
        f32x4 y1[2], oo[2];
#pragma unroll
        for (int nj = 0; nj < 2; nj++) {
            y1[nj] = (f32x4){0.f, 0.f, 0.f, 0.f};
            oo[nj] = (f32x4){0.f, 0.f, 0.f, 0.f};
        }
#pragma unroll
        for (int kk = 0; kk < 4; kk++) {
#pragma unroll
            for (int nj = 0; nj < 2; nj++) {
                bf16x8 bb = *(const bf16x8*)&SbfT[nj * 16 + l15][kk * 32 + quad * 8];
                y1[nj] = MFMA16(aTw[kk], bb, y1[nj]);
                oo[nj] = MFMA16(aQ2[kk], bb, oo[nj]);
            }
        }
        // U = Tv - Y1 ; O += O_loc (uses tvv_pf / oold)
#pragma unroll
        for (int nj = 0; nj < 2; nj++)
#pragma unroll
            for (int r = 0; r < 4; r++) {
                int i = w * 16 + quad * 4 + r;
                int vl = nj * 16 + l15;
                int vg = vq * 32 + vl;
                Ut[vl][i] = f2bf(bf2f(tvv_pf[nj][r]) - y1[nj][r]);
                obuf[(tokbase + i) * 4096 + h * 128 + vg] =
                    f2bf(bf2f(oold[nj][r]) + oo[nj][r]);
            }
        __syncthreads();

        // prefetch next step (pure global loads, independent of LDS)
        if (c + 1 < 32) PB_PREFETCH(c + 1);

        // group 2: S = A_C*S + KhT^T U
#pragma unroll
        for (int mm = 0; mm < 2; mm++) {
            int mi = 2 * w + mm;
#pragma unroll
            for (int nj = 0; nj < 2; nj++) {
                f32x4 sacc;
#pragma unroll
                for (int r = 0; r < 4; r++)
                    sacc[r] = A_C * Sf[mi * 16 + quad * 4 + r][nj * 16 + l15];
#pragma unroll
                for (int kk = 0; kk < 2; kk++) {
                    bf16x8 a = *(const bf16x8*)&KhT[mi * 16 + l15][kk * 32 + quad * 8];
                    bf16x8 bb = *(const bf16x8*)&Ut[nj * 16 + l15][kk * 32 + quad * 8];
                    sacc = MFMA16(a, bb, sacc);
                }
#pragma unroll
                for (int r = 0; r < 4; r++) {
                    int kd = mi * 16 + quad * 4 + r, vl = nj * 16 + l15;
                    Sf[kd][vl] = sacc[r];
                    SbfT[vl][kd] = f2bf(sacc[r]);
                }
            }
        }
        __syncthreads();
    }
#undef PB_PREFETCH
}

// ---------------- gated RMSNorm ----------------
__global__ __launch_bounds__(256) void gated_norm(const u16* __restrict__ obuf,
                                                  const u16* __restrict__ zbuf,
                                                  const float* __restrict__ norm_w,
                                                  u16* __restrict__ xn) {
    int tok = blockIdx.x, tid = threadIdx.x;
    long obase = (long)tok * 4096 + tid * 16;
    u16 ob[16], zb[16];
    *(uint4*)(ob + 0) = *(const uint4*)&obuf[obase];
    *(uint4*)(ob + 8) = *(const uint4*)&obuf[obase + 8];
    *(uint4*)(zb + 0) = *(const uint4*)&zbuf[obase];
    *(uint4*)(zb + 8) = *(const uint4*)&zbuf[obase + 8];
    float x[16];
    float ss = 0.f;
#pragma unroll
    for (int i = 0; i < 16; i++) {
        float ov = bf2f(ob[i]);
        float zv = bf2f(zb[i]);
        float xv = ov * (zv / (1.f + expf(-zv)));
        x[i] = xv;
        ss += xv * xv;
    }
    ss += __shfl_xor(ss, 4, 8);
    ss += __shfl_xor(ss, 2, 8);
    ss += __shfl_xor(ss, 1, 8);
    float scale = rsqrtf(ss * (1.f / 128.f) + 1e-6f);
    int cbase = (tid * 16) & 127;
#pragma unroll
    for (int i = 0; i < 16; i++)
        xn[(long)tok * 4096 + tid * 16 + i] = f2bf(x[i] * scale * (1.f + norm_w[cbase + i]));
}

// ---------------- launch ----------------
extern "C" void kernel_launch(void* const* d_in, const int* in_sizes, int n_in, void* d_out,
                              int out_size, void* d_ws, size_t ws_size, hipStream_t stream) {
    const float* hidden = (const float*)d_in[0];
    const float* W_qkvz = (const float*)d_in[1];
    const float* W_ba = (const float*)d_in[2];
    const float* conv_w = (const float*)d_in[3];
    const float* A_log = (const float*)d_in[4];
    const float* dt_bias = (const float*)d_in[5];
    const float* norm_w = (const float*)d_in[6];
    const float* W_out = (const float*)d_in[7];
    float* out = (float*)d_out;

    char* ws = (char*)d_ws;
    u16* wqT = (u16*)(ws + 0);
    u16* qn = (u16*)(ws + 0);
    u16* vc = (u16*)(ws + 16777216L);
    u16* hidbf = (u16*)(ws + 50331648L);
    u16* kn = (u16*)(ws + 50331648L);
    u16* woT = (u16*)(ws + 67108864L);
    u16* qkv_raw = (u16*)(ws + 83886080L);
    u16* Tv = (u16*)(ws + 83886080L);
    u16* Tw = (u16*)(ws + 117440512L);
    u16* xn = (u16*)(ws + 83886080L);
    u16* WbaT = (u16*)(ws + 150994944L);
    u16* zbuf = (u16*)(ws + 150994944L);
    u16* Q2 = (u16*)(ws + 184549376L);
    float* g = (float*)(ws + 218103808L);
    float* beta = (float*)(ws + 218628096L);
    u16* obuf = vc;

    cast_f32_bf16<<<8192, 256, 0, stream>>>(hidden, hidbf, 8388608L);
    transpose_cast<<<dim3(384, 64), 256, 0, stream>>>(W_qkvz, wqT, 2048, 12288);
    transpose_cast<<<dim3(64, 128), 256, 0, stream>>>(W_out, woT, 4096, 2048);
    transpose_cast<<<dim3(2, 64), 256, 0, stream>>>(W_ba, WbaT, 2048, 64);
    ba_gemm<<<128, 256, 0, stream>>>(hidbf, WbaT, A_log, dt_bias, g, beta);
    gemm_bt<2><<<dim3(32, 96), 256, 0, stream>>>(hidbf, wqT, qkv_raw, zbuf, 4096, 12288, 2048,
                                                 2048, 2048, 0);
    conv_gate<<<4096, 256, 0, stream>>>(qkv_raw, conv_w, qn, kn, vc);
    phaseA<<<2048, 256, 0, stream>>>(qn, kn, vc, g, beta, Tv, Tw, Q2, obuf);
    phaseB<<<256, 256, 0, stream>>>(kn, g, Tv, Tw, Q2, obuf);
    gated_norm<<<4096, 256, 0, stream>>>(obuf, zbuf, norm_w, xn);
    gemm_bt<0><<<dim3(32, 16), 256, 0, stream>>>(xn, woT, out, nullptr, 4096, 2048, 4096, 4096,
                                                 4096, 2048);
}